// Round 3
// baseline (3340.719 us; speedup 1.0000x reference)
//
#include <hip/hip_runtime.h>

#define DM    128
#define NHEAD 2
#define HIDC  64
#define OUTC  32
#define NG    64
#define EPS   1e-5f

// ---------------------------------------------------------------------------
// GEMM per node row: H = X @ W  (+ optional S = X @ Wskip + bskip)
// plus per-head attention dots a_src/a_dst via wave reduction.
// block = 128 threads (2 waves of 64; wave id == head id), grid = N
// ---------------------------------------------------------------------------
__global__ void gemm_attn_kernel(const float* __restrict__ X,
                                 const float* __restrict__ W,
                                 const float* __restrict__ Wskip,   // nullable
                                 const float* __restrict__ bskip,   // nullable
                                 const float* __restrict__ att_src,
                                 const float* __restrict__ att_dst,
                                 float* __restrict__ H,
                                 float* __restrict__ S,             // nullable
                                 float* __restrict__ a_src,
                                 float* __restrict__ a_dst)
{
    __shared__ float xr[DM];
    const int n = blockIdx.x;
    const int t = threadIdx.x;
    xr[t] = X[n * DM + t];
    __syncthreads();

    float acc = 0.f, accs = 0.f;
    if (Wskip) {
#pragma unroll
        for (int k = 0; k < DM; ++k) {
            float xv = xr[k];
            acc  += xv * W[k * DM + t];
            accs += xv * Wskip[k * DM + t];
        }
    } else {
#pragma unroll
        for (int k = 0; k < DM; ++k) acc += xr[k] * W[k * DM + t];
    }
    H[n * DM + t] = acc;
    if (S) S[n * DM + t] = accs + bskip[t];

    const int lane = t & 63, head = t >> 6;
    float vs = acc * att_src[head * HIDC + lane];
    float vd = acc * att_dst[head * HIDC + lane];
#pragma unroll
    for (int off = 32; off; off >>= 1) {
        vs += __shfl_down(vs, off);
        vd += __shfl_down(vd, off);
    }
    if (lane == 0) {
        a_src[n * NHEAD + head] = vs;
        a_dst[n * NHEAD + head] = vd;
    }
}

// ---------------------------------------------------------------------------
// Edge pass 1: ee = exp(leaky_relu(a_src[s]+a_dst[d])); denom[d] += ee
// one thread per (edge, head). Self loops: e >= E -> s = d = e - E.
// ---------------------------------------------------------------------------
__global__ void edge_logits_kernel(const int* __restrict__ ei, int E, int Ep,
                                   const float* __restrict__ a_src,
                                   const float* __restrict__ a_dst,
                                   float* __restrict__ ebuf,
                                   float* __restrict__ denom)
{
    int idx = blockIdx.x * blockDim.x + threadIdx.x;
    if (idx >= Ep * NHEAD) return;
    int e = idx >> 1, head = idx & 1;
    int s, d;
    if (e < E) { s = ei[e]; d = ei[E + e]; } else { s = e - E; d = s; }
    float v = a_src[s * NHEAD + head] + a_dst[d * NHEAD + head];
    v = v > 0.f ? v : 0.2f * v;
    float ee = expf(v);
    ebuf[idx] = ee;
    atomicAdd(&denom[d * NHEAD + head], ee);
}

// ---------------------------------------------------------------------------
// Edge pass 2: agg[d, c] += H[s, c] * (ee / denom[d])
// one thread per (edge, 4 channels); 32 consecutive threads = one edge.
// float4 gather of H; 4 scalar atomics (no vector float atomics on gfx950).
// ---------------------------------------------------------------------------
__global__ void edge_msg_kernel(const int* __restrict__ ei, int E, int Ep,
                                const float* __restrict__ H,
                                const float* __restrict__ ebuf,
                                const float* __restrict__ denom,
                                float* __restrict__ agg)
{
    long long idx = (long long)blockIdx.x * blockDim.x + threadIdx.x;
    if (idx >= (long long)Ep * 32) return;
    int e = (int)(idx >> 5);
    int c = ((int)idx & 31) * 4;
    int s, d;
    if (e < E) { s = ei[e]; d = ei[E + e]; } else { s = e - E; d = s; }
    int head = c >> 6;
    float alpha = ebuf[e * NHEAD + head] / denom[d * NHEAD + head];
    const float4 h = *(const float4*)&H[s * DM + c];
    float* ap = &agg[d * DM + c];
    atomicAdd(ap + 0, h.x * alpha);
    atomicAdd(ap + 1, h.y * alpha);
    atomicAdd(ap + 2, h.z * alpha);
    atomicAdd(ap + 3, h.w * alpha);
}

// ---------------------------------------------------------------------------
// LayerNorm row kernel: v = agg + bias (+ res); y = elu(LN(v)); out = y (+ skip)
// block = 128 (2 waves), grid = N. In-place safe (each thread owns its elem).
// ---------------------------------------------------------------------------
__global__ void ln_kernel(const float* __restrict__ agg,
                          const float* __restrict__ bias,
                          const float* __restrict__ res,    // nullable, added pre-LN
                          const float* __restrict__ lng,
                          const float* __restrict__ lnb,
                          const float* __restrict__ skip,   // nullable, added post-ELU
                          float* __restrict__ out)
{
    const int n = blockIdx.x, t = threadIdx.x;
    const int i = n * DM + t;
    float v = agg[i] + bias[t];
    if (res) v += res[i];

    __shared__ float red[2];
    const int lane = t & 63, wave = t >> 6;

    float s = v;
#pragma unroll
    for (int off = 32; off; off >>= 1) s += __shfl_down(s, off);
    if (lane == 0) red[wave] = s;
    __syncthreads();
    float mean = (red[0] + red[1]) * (1.f / DM);
    __syncthreads();

    float dv = v - mean;
    float s2 = dv * dv;
#pragma unroll
    for (int off = 32; off; off >>= 1) s2 += __shfl_down(s2, off);
    if (lane == 0) red[wave] = s2;
    __syncthreads();
    float var = (red[0] + red[1]) * (1.f / DM);

    float y = dv * rsqrtf(var + EPS) * lng[t] + lnb[t];
    y = y > 0.f ? y : expm1f(y);   // ELU
    if (skip) y += skip[i];
    out[i] = y;
}

// ---------------------------------------------------------------------------
// Global mean pool: batch is SORTED -> each block owns a contiguous node
// chunk, accumulates per-graph partials in registers, flushes one atomic
// per (block, graph-run, channel). thread t = channel c.
// ---------------------------------------------------------------------------
__global__ void pool_kernel(const float* __restrict__ emb,
                            const int* __restrict__ batch, int N,
                            float* __restrict__ sums,
                            float* __restrict__ cnt)
{
    const int t = threadIdx.x;
    const int chunk = (N + gridDim.x - 1) / gridDim.x;
    const int n0 = blockIdx.x * chunk;
    const int n1 = min(N, n0 + chunk);
    if (n0 >= n1) return;

    int cur = batch[n0];
    float acc = 0.f;
    int count = 0;
    for (int n = n0; n < n1; ++n) {
        int b = batch[n];
        if (b != cur) {
            atomicAdd(&sums[cur * DM + t], acc);
            if (t == 0) atomicAdd(&cnt[cur], (float)count);
            acc = 0.f; count = 0; cur = b;
        }
        acc += emb[n * DM + t];
        ++count;
    }
    atomicAdd(&sums[cur * DM + t], acc);
    if (t == 0) atomicAdd(&cnt[cur], (float)count);
}

// ---------------------------------------------------------------------------
// Head: graph_emb = sums/cnt; logits = ge @ Wfc + bfc; BatchNorm over graphs.
// single block, 1024 threads.
// ---------------------------------------------------------------------------
__global__ void head_kernel(const float* __restrict__ sums,
                            const float* __restrict__ cnt,
                            const float* __restrict__ Wfc,
                            const float* __restrict__ bfc,
                            const float* __restrict__ bn_g,
                            const float* __restrict__ bn_b,
                            float* __restrict__ out)
{
    __shared__ float ge[NG * DM];
    __shared__ float lg[NG * OUTC];
    __shared__ float mu[OUTC], inv[OUTC];
    const int t = threadIdx.x;

    for (int i = t; i < NG * DM; i += blockDim.x) {
        int g = i >> 7;
        ge[i] = sums[i] / fmaxf(cnt[g], 1.0f);
    }
    __syncthreads();

    for (int i = t; i < NG * OUTC; i += blockDim.x) {
        int g = i >> 5, o = i & (OUTC - 1);
        float acc = bfc[o];
#pragma unroll
        for (int k = 0; k < DM; ++k) acc += ge[g * DM + k] * Wfc[k * OUTC + o];
        lg[i] = acc;
    }
    __syncthreads();

    if (t < OUTC) {
        float s = 0.f;
        for (int g = 0; g < NG; ++g) s += lg[g * OUTC + t];
        float m = s * (1.f / NG);
        float v = 0.f;
        for (int g = 0; g < NG; ++g) { float d = lg[g * OUTC + t] - m; v += d * d; }
        v *= (1.f / NG);
        mu[t] = m;
        inv[t] = rsqrtf(v + EPS) * bn_g[t];
    }
    __syncthreads();

    for (int i = t; i < NG * OUTC; i += blockDim.x) {
        int o = i & (OUTC - 1);
        out[i] = (lg[i] - mu[o]) * inv[o] + bn_b[o];
    }
}

// ---------------------------------------------------------------------------
extern "C" void kernel_launch(void* const* d_in, const int* in_sizes, int n_in,
                              void* d_out, int out_size, void* d_ws, size_t ws_size,
                              hipStream_t stream)
{
    const float* x     = (const float*)d_in[0];
    const int*   ei    = (const int*)  d_in[1];
    const int*   batch = (const int*)  d_in[2];
    const float* W1    = (const float*)d_in[3];
    const float* as1   = (const float*)d_in[4];
    const float* ad1   = (const float*)d_in[5];
    const float* b1    = (const float*)d_in[6];
    const float* ln1g  = (const float*)d_in[7];
    const float* ln1b  = (const float*)d_in[8];
    const float* Wskip = (const float*)d_in[9];
    const float* bskip = (const float*)d_in[10];
    const float* W2    = (const float*)d_in[11];
    const float* as2   = (const float*)d_in[12];
    const float* ad2   = (const float*)d_in[13];
    const float* b2    = (const float*)d_in[14];
    const float* ln2g  = (const float*)d_in[15];
    const float* ln2b  = (const float*)d_in[16];
    const float* Wfc   = (const float*)d_in[17];
    const float* bfc   = (const float*)d_in[18];
    const float* bng   = (const float*)d_in[19];
    const float* bnb   = (const float*)d_in[20];

    const int N  = in_sizes[2];
    const int E  = in_sizes[1] / 2;
    const int Ep = E + N;

    size_t off = 0;
    auto alloc = [&](size_t bytes) -> float* {
        float* p = (float*)((char*)d_ws + off);
        off += (bytes + 255) & ~(size_t)255;
        return p;
    };
    float* Hbuf  = alloc((size_t)N * DM * 4);          // h1, then h2
    float* Buf1  = alloc((size_t)N * DM * 4);          // agg1 -> x1 (kept for residual)
    float* Buf2  = alloc((size_t)N * DM * 4);          // skip -> agg2 -> emb
    float* ebuf  = alloc((size_t)Ep * NHEAD * 4);      // per-edge exp(e)
    float* denom = alloc((size_t)N * NHEAD * 4);
    float* asrc  = alloc((size_t)N * NHEAD * 4);
    float* adst  = alloc((size_t)N * NHEAD * 4);
    float* sums  = alloc((size_t)(NG * DM + NG) * 4);  // sums | cnt contiguous
    float* cnt   = sums + NG * DM;

    const int eb1 = (Ep * NHEAD + 255) / 256;
    const int eb2 = (int)(((long long)Ep * 32 + 255) / 256);

    // ---- layer 1 ----
    gemm_attn_kernel<<<N, DM, 0, stream>>>(x, W1, Wskip, bskip, as1, ad1,
                                           Hbuf, Buf2, asrc, adst);
    hipMemsetAsync(denom, 0, (size_t)N * NHEAD * 4, stream);
    hipMemsetAsync(Buf1, 0, (size_t)N * DM * 4, stream);
    edge_logits_kernel<<<eb1, 256, 0, stream>>>(ei, E, Ep, asrc, adst, ebuf, denom);
    edge_msg_kernel<<<eb2, 256, 0, stream>>>(ei, E, Ep, Hbuf, ebuf, denom, Buf1);
    ln_kernel<<<N, DM, 0, stream>>>(Buf1, b1, nullptr, ln1g, ln1b, Buf2, Buf1);

    // ---- layer 2 ----
    gemm_attn_kernel<<<N, DM, 0, stream>>>(Buf1, W2, nullptr, nullptr, as2, ad2,
                                           Hbuf, nullptr, asrc, adst);
    hipMemsetAsync(denom, 0, (size_t)N * NHEAD * 4, stream);
    hipMemsetAsync(Buf2, 0, (size_t)N * DM * 4, stream);
    edge_logits_kernel<<<eb1, 256, 0, stream>>>(ei, E, Ep, asrc, adst, ebuf, denom);
    edge_msg_kernel<<<eb2, 256, 0, stream>>>(ei, E, Ep, Hbuf, ebuf, denom, Buf2);
    ln_kernel<<<N, DM, 0, stream>>>(Buf2, b2, Buf1, ln2g, ln2b, nullptr, Buf2);

    // ---- pool + head ----
    hipMemsetAsync(sums, 0, (size_t)(NG * DM + NG) * 4, stream);
    pool_kernel<<<1024, DM, 0, stream>>>(Buf2, batch, N, sums, cnt);
    head_kernel<<<1, 1024, 0, stream>>>(sums, cnt, Wfc, bfc, bng, bnb, (float*)d_out);
}

// Round 4
// 686.530 us; speedup vs baseline: 4.8661x; 4.8661x over previous
//
#include <hip/hip_runtime.h>

#define DM    128
#define NHEAD 2
#define HIDC  64
#define OUTC  32
#define NG    64
#define EPS   1e-5f

// ---------------------------------------------------------------------------
// GEMM per node row: H = X @ W  (+ optional S = X @ Wskip + bskip)
// plus per-head attention dots a_src/a_dst via wave reduction.
// block = 128 threads (2 waves of 64; wave id == head id), grid = N
// ---------------------------------------------------------------------------
__global__ void gemm_attn_kernel(const float* __restrict__ X,
                                 const float* __restrict__ W,
                                 const float* __restrict__ Wskip,   // nullable
                                 const float* __restrict__ bskip,   // nullable
                                 const float* __restrict__ att_src,
                                 const float* __restrict__ att_dst,
                                 float* __restrict__ H,
                                 float* __restrict__ S,             // nullable
                                 float* __restrict__ a_src,
                                 float* __restrict__ a_dst)
{
    __shared__ float xr[DM];
    const int n = blockIdx.x;
    const int t = threadIdx.x;
    xr[t] = X[n * DM + t];
    __syncthreads();

    float acc = 0.f, accs = 0.f;
    if (Wskip) {
#pragma unroll
        for (int k = 0; k < DM; ++k) {
            float xv = xr[k];
            acc  += xv * W[k * DM + t];
            accs += xv * Wskip[k * DM + t];
        }
    } else {
#pragma unroll
        for (int k = 0; k < DM; ++k) acc += xr[k] * W[k * DM + t];
    }
    H[n * DM + t] = acc;
    if (S) S[n * DM + t] = accs + bskip[t];

    const int lane = t & 63, head = t >> 6;
    float vs = acc * att_src[head * HIDC + lane];
    float vd = acc * att_dst[head * HIDC + lane];
#pragma unroll
    for (int off = 32; off; off >>= 1) {
        vs += __shfl_down(vs, off);
        vd += __shfl_down(vd, off);
    }
    if (lane == 0) {
        a_src[n * NHEAD + head] = vs;
        a_dst[n * NHEAD + head] = vd;
    }
}

// ---------------------------------------------------------------------------
// CSR build: degree histogram -> exclusive scan -> scatter src ids.
// Self loops are NOT stored; the agg kernel adds them inline.
// ---------------------------------------------------------------------------
__global__ void deg_kernel(const int* __restrict__ ei, int E, int* __restrict__ deg)
{
    int e = blockIdx.x * blockDim.x + threadIdx.x;
    if (e < E) atomicAdd(&deg[ei[E + e]], 1);
}

__global__ void scan_kernel(const int* __restrict__ deg, int N,
                            int* __restrict__ rowptr, int* __restrict__ cursor)
{
    __shared__ int buf[1024];
    __shared__ int carry;
    const int t = threadIdx.x;
    if (t == 0) carry = 0;
    __syncthreads();
    for (int base = 0; base < N; base += 1024) {
        int i = base + t;
        int v = (i < N) ? deg[i] : 0;
        buf[t] = v;
        __syncthreads();
        for (int off = 1; off < 1024; off <<= 1) {
            int x = (t >= off) ? buf[t - off] : 0;
            __syncthreads();
            buf[t] += x;
            __syncthreads();
        }
        int excl = carry + buf[t] - v;
        if (i < N) { rowptr[i] = excl; cursor[i] = excl; }
        __syncthreads();
        if (t == 1023) carry += buf[1023];
        __syncthreads();
    }
    if (t == 0) rowptr[N] = carry;
}

__global__ void scatter_kernel(const int* __restrict__ ei, int E,
                               int* __restrict__ cursor, int* __restrict__ col)
{
    int e = blockIdx.x * blockDim.x + threadIdx.x;
    if (e < E) {
        int d = ei[E + e];
        int p = atomicAdd(&cursor[d], 1);
        col[p] = ei[e];
    }
}

// ---------------------------------------------------------------------------
// Fused GAT aggregation + bias + (res) + LayerNorm + ELU + (skip).
// One block per dst node, thread t = channel. Gathers incident edges via CSR,
// accumulates unnormalized message & denominator in registers (no atomics):
//   out_c = sum_e ee_e * H[s_e, c] / sum_e ee_e
// Self loop (s = d) added inline.
// ---------------------------------------------------------------------------
__global__ void gat_agg_ln_kernel(const int* __restrict__ rowptr,
                                  const int* __restrict__ col,
                                  const float* __restrict__ H,
                                  const float* __restrict__ a_src,
                                  const float* __restrict__ a_dst,
                                  const float* __restrict__ bias,
                                  const float* __restrict__ res,    // nullable, pre-LN
                                  const float* __restrict__ lng,
                                  const float* __restrict__ lnb,
                                  const float* __restrict__ skip,   // nullable, post-ELU
                                  float* __restrict__ out)
{
    const int d = blockIdx.x, t = threadIdx.x;
    const int lane = t & 63, head = t >> 6;

    const float ad0 = a_dst[d * NHEAD + head];

    // self loop
    float e0 = a_src[d * NHEAD + head] + ad0;
    e0 = e0 > 0.f ? e0 : 0.2f * e0;
    float w = __expf(e0);
    float den = w;
    float acc = w * H[d * DM + t];

    int p = rowptr[d];
    const int p1 = rowptr[d + 1];
    for (; p + 1 < p1; p += 2) {
        int s0 = col[p], s1 = col[p + 1];
        float ea = a_src[s0 * NHEAD + head] + ad0;
        float eb = a_src[s1 * NHEAD + head] + ad0;
        float h0 = H[s0 * DM + t];
        float h1 = H[s1 * DM + t];
        ea = ea > 0.f ? ea : 0.2f * ea;
        eb = eb > 0.f ? eb : 0.2f * eb;
        float wa = __expf(ea), wb = __expf(eb);
        den += wa + wb;
        acc += wa * h0 + wb * h1;
    }
    if (p < p1) {
        int s0 = col[p];
        float ea = a_src[s0 * NHEAD + head] + ad0;
        float h0 = H[s0 * DM + t];
        ea = ea > 0.f ? ea : 0.2f * ea;
        float wa = __expf(ea);
        den += wa;
        acc += wa * h0;
    }

    const int i = d * DM + t;
    float v = acc / den + bias[t];
    if (res) v += res[i];

    // LayerNorm across the 128 channels (2 waves)
    __shared__ float red[2];
    float s = v;
#pragma unroll
    for (int off = 32; off; off >>= 1) s += __shfl_down(s, off);
    if (lane == 0) red[head] = s;
    __syncthreads();
    float mean = (red[0] + red[1]) * (1.f / DM);
    __syncthreads();

    float dv = v - mean;
    float s2 = dv * dv;
#pragma unroll
    for (int off = 32; off; off >>= 1) s2 += __shfl_down(s2, off);
    if (lane == 0) red[head] = s2;
    __syncthreads();
    float var = (red[0] + red[1]) * (1.f / DM);

    float y = dv * rsqrtf(var + EPS) * lng[t] + lnb[t];
    y = y > 0.f ? y : expm1f(y);   // ELU
    if (skip) y += skip[i];
    out[i] = y;
}

// ---------------------------------------------------------------------------
// Global mean pool: batch is SORTED -> each block owns a contiguous node
// chunk, accumulates per-graph partials in registers, flushes one atomic
// per (block, graph-run, channel). thread t = channel c.
// ---------------------------------------------------------------------------
__global__ void pool_kernel(const float* __restrict__ emb,
                            const int* __restrict__ batch, int N,
                            float* __restrict__ sums,
                            float* __restrict__ cnt)
{
    const int t = threadIdx.x;
    const int chunk = (N + gridDim.x - 1) / gridDim.x;
    const int n0 = blockIdx.x * chunk;
    const int n1 = min(N, n0 + chunk);
    if (n0 >= n1) return;

    int cur = batch[n0];
    float acc = 0.f;
    int count = 0;
    for (int n = n0; n < n1; ++n) {
        int b = batch[n];
        if (b != cur) {
            atomicAdd(&sums[cur * DM + t], acc);
            if (t == 0) atomicAdd(&cnt[cur], (float)count);
            acc = 0.f; count = 0; cur = b;
        }
        acc += emb[n * DM + t];
        ++count;
    }
    atomicAdd(&sums[cur * DM + t], acc);
    if (t == 0) atomicAdd(&cnt[cur], (float)count);
}

// ---------------------------------------------------------------------------
// Head: graph_emb = sums/cnt; logits = ge @ Wfc + bfc; BatchNorm over graphs.
// single block, 1024 threads.
// ---------------------------------------------------------------------------
__global__ void head_kernel(const float* __restrict__ sums,
                            const float* __restrict__ cnt,
                            const float* __restrict__ Wfc,
                            const float* __restrict__ bfc,
                            const float* __restrict__ bn_g,
                            const float* __restrict__ bn_b,
                            float* __restrict__ out)
{
    __shared__ float ge[NG * DM];
    __shared__ float lg[NG * OUTC];
    __shared__ float mu[OUTC], inv[OUTC];
    const int t = threadIdx.x;

    for (int i = t; i < NG * DM; i += blockDim.x) {
        int g = i >> 7;
        ge[i] = sums[i] / fmaxf(cnt[g], 1.0f);
    }
    __syncthreads();

    for (int i = t; i < NG * OUTC; i += blockDim.x) {
        int g = i >> 5, o = i & (OUTC - 1);
        float acc = bfc[o];
#pragma unroll
        for (int k = 0; k < DM; ++k) acc += ge[g * DM + k] * Wfc[k * OUTC + o];
        lg[i] = acc;
    }
    __syncthreads();

    if (t < OUTC) {
        float s = 0.f;
        for (int g = 0; g < NG; ++g) s += lg[g * OUTC + t];
        float m = s * (1.f / NG);
        float v = 0.f;
        for (int g = 0; g < NG; ++g) { float d = lg[g * OUTC + t] - m; v += d * d; }
        v *= (1.f / NG);
        mu[t] = m;
        inv[t] = rsqrtf(v + EPS) * bn_g[t];
    }
    __syncthreads();

    for (int i = t; i < NG * OUTC; i += blockDim.x) {
        int o = i & (OUTC - 1);
        out[i] = (lg[i] - mu[o]) * inv[o] + bn_b[o];
    }
}

// ---------------------------------------------------------------------------
extern "C" void kernel_launch(void* const* d_in, const int* in_sizes, int n_in,
                              void* d_out, int out_size, void* d_ws, size_t ws_size,
                              hipStream_t stream)
{
    const float* x     = (const float*)d_in[0];
    const int*   ei    = (const int*)  d_in[1];
    const int*   batch = (const int*)  d_in[2];
    const float* W1    = (const float*)d_in[3];
    const float* as1   = (const float*)d_in[4];
    const float* ad1   = (const float*)d_in[5];
    const float* b1    = (const float*)d_in[6];
    const float* ln1g  = (const float*)d_in[7];
    const float* ln1b  = (const float*)d_in[8];
    const float* Wskip = (const float*)d_in[9];
    const float* bskip = (const float*)d_in[10];
    const float* W2    = (const float*)d_in[11];
    const float* as2   = (const float*)d_in[12];
    const float* ad2   = (const float*)d_in[13];
    const float* b2    = (const float*)d_in[14];
    const float* ln2g  = (const float*)d_in[15];
    const float* ln2b  = (const float*)d_in[16];
    const float* Wfc   = (const float*)d_in[17];
    const float* bfc   = (const float*)d_in[18];
    const float* bng   = (const float*)d_in[19];
    const float* bnb   = (const float*)d_in[20];

    const int N  = in_sizes[2];
    const int E  = in_sizes[1] / 2;

    size_t off = 0;
    auto alloc = [&](size_t bytes) -> char* {
        char* p = (char*)d_ws + off;
        off += (bytes + 255) & ~(size_t)255;
        return p;
    };
    float* Hbuf   = (float*)alloc((size_t)N * DM * 4);   // h1, then h2
    float* Buf1   = (float*)alloc((size_t)N * DM * 4);   // x1 (kept for residual)
    float* Buf2   = (float*)alloc((size_t)N * DM * 4);   // skip -> emb
    float* asrc   = (float*)alloc((size_t)N * NHEAD * 4);
    float* adst   = (float*)alloc((size_t)N * NHEAD * 4);
    int*   deg    = (int*)  alloc((size_t)N * 4);
    int*   rowptr = (int*)  alloc((size_t)(N + 1) * 4);
    int*   cursor = (int*)  alloc((size_t)N * 4);
    int*   col    = (int*)  alloc((size_t)E * 4);
    float* sums   = (float*)alloc((size_t)(NG * DM + NG) * 4);
    float* cnt    = sums + NG * DM;

    const int eb = (E + 255) / 256;

    // ---- CSR build (shared by both layers) ----
    hipMemsetAsync(deg, 0, (size_t)N * 4, stream);
    deg_kernel<<<eb, 256, 0, stream>>>(ei, E, deg);
    scan_kernel<<<1, 1024, 0, stream>>>(deg, N, rowptr, cursor);
    scatter_kernel<<<eb, 256, 0, stream>>>(ei, E, cursor, col);

    // ---- layer 1 ----
    gemm_attn_kernel<<<N, DM, 0, stream>>>(x, W1, Wskip, bskip, as1, ad1,
                                           Hbuf, Buf2, asrc, adst);
    gat_agg_ln_kernel<<<N, DM, 0, stream>>>(rowptr, col, Hbuf, asrc, adst,
                                            b1, nullptr, ln1g, ln1b, Buf2, Buf1);

    // ---- layer 2 ----
    gemm_attn_kernel<<<N, DM, 0, stream>>>(Buf1, W2, nullptr, nullptr, as2, ad2,
                                           Hbuf, nullptr, asrc, adst);
    gat_agg_ln_kernel<<<N, DM, 0, stream>>>(rowptr, col, Hbuf, asrc, adst,
                                            b2, Buf1, ln2g, ln2b, nullptr, Buf2);

    // ---- pool + head ----
    hipMemsetAsync(sums, 0, (size_t)(NG * DM + NG) * 4, stream);
    pool_kernel<<<1024, DM, 0, stream>>>(Buf2, batch, N, sums, cnt);
    head_kernel<<<1, 1024, 0, stream>>>(sums, cnt, Wfc, bfc, bng, bnb, (float*)d_out);
}

// Round 6
// 466.261 us; speedup vs baseline: 7.1649x; 1.4724x over previous
//
#include <hip/hip_runtime.h>

#define DM    128
#define NHEAD 2
#define HIDC  64
#define OUTC  32
#define NG    64
#define EPS   1e-5f
#define TM    32     // rows per GEMM block

// ---------------------------------------------------------------------------
// Tiled GEMM: C[n0..n0+TM) x [0..128) = X-chunk @ W  (+bias) (+att dots).
// W (64 KB) + X chunk (16 KB) staged in LDS -> 80 KB, 2 blocks/CU.
// 256 threads; thread t owns 4 rows x 4 cols: r0=(t>>5)*4, c4=(t&31)*4.
// ---------------------------------------------------------------------------
__global__ __launch_bounds__(256) void gemm_tile_kernel(
    const float* __restrict__ X, int N,
    const float* __restrict__ W,
    const float* __restrict__ bias,      // nullable
    const float* __restrict__ att_src,   // nullable (with att_dst)
    const float* __restrict__ att_dst,
    float* __restrict__ C,
    float* __restrict__ a_src,
    float* __restrict__ a_dst)
{
    __shared__ float Ws[DM * DM];        // 64 KB
    __shared__ float Xs[TM * DM];        // 16 KB
    const int t  = threadIdx.x;
    const int n0 = blockIdx.x * TM;

    // stage W: 16384 floats = 4096 float4, 16 per thread
    {
        const float4* Wv  = (const float4*)W;
        float4*       Wsv = (float4*)Ws;
#pragma unroll
        for (int i = 0; i < 16; ++i)
            Wsv[t + i * 256] = Wv[t + i * 256];
    }
    // stage X chunk: 4096 floats = 1024 float4 = 4 float4/thread (zero-pad past N)
    {
#pragma unroll
        for (int i = 0; i < 4; ++i) {
            const int idx = (t + i * 256) * 4;
            const int n = n0 + (idx >> 7);
            float4 v = make_float4(0.f, 0.f, 0.f, 0.f);
            if (n < N) v = *(const float4*)&X[n * DM + (idx & 127)];
            *(float4*)&Xs[idx] = v;
        }
    }
    __syncthreads();

    const int c4 = (t & 31) * 4;
    const int r0 = (t >> 5) * 4;

    float acc[4][4];
#pragma unroll
    for (int i = 0; i < 4; ++i)
#pragma unroll
        for (int j = 0; j < 4; ++j) acc[i][j] = 0.f;

#pragma unroll 4
    for (int k = 0; k < DM; ++k) {
        const float4 wv = *(const float4*)&Ws[k * DM + c4];
        const float x0 = Xs[(r0 + 0) * DM + k];
        const float x1 = Xs[(r0 + 1) * DM + k];
        const float x2 = Xs[(r0 + 2) * DM + k];
        const float x3 = Xs[(r0 + 3) * DM + k];
        acc[0][0] += x0 * wv.x; acc[0][1] += x0 * wv.y; acc[0][2] += x0 * wv.z; acc[0][3] += x0 * wv.w;
        acc[1][0] += x1 * wv.x; acc[1][1] += x1 * wv.y; acc[1][2] += x1 * wv.z; acc[1][3] += x1 * wv.w;
        acc[2][0] += x2 * wv.x; acc[2][1] += x2 * wv.y; acc[2][2] += x2 * wv.z; acc[2][3] += x2 * wv.w;
        acc[3][0] += x3 * wv.x; acc[3][1] += x3 * wv.y; acc[3][2] += x3 * wv.z; acc[3][3] += x3 * wv.w;
    }

    if (bias) {
        const float4 bv = *(const float4*)&bias[c4];
#pragma unroll
        for (int i = 0; i < 4; ++i) {
            acc[i][0] += bv.x; acc[i][1] += bv.y; acc[i][2] += bv.z; acc[i][3] += bv.w;
        }
    }

    float4 avs, avd;
    if (att_src) {
        avs = *(const float4*)&att_src[c4];   // att flat [h*64+c] == [c4..]
        avd = *(const float4*)&att_dst[c4];
    }

#pragma unroll
    for (int i = 0; i < 4; ++i) {
        const int n = n0 + r0 + i;
        if (n < N) {
            float4 o = make_float4(acc[i][0], acc[i][1], acc[i][2], acc[i][3]);
            *(float4*)&C[n * DM + c4] = o;
            if (att_src) {
                float vs = o.x * avs.x + o.y * avs.y + o.z * avs.z + o.w * avs.w;
                float vd = o.x * avd.x + o.y * avd.y + o.z * avd.z + o.w * avd.w;
#pragma unroll
                for (int off = 8; off; off >>= 1) {
                    vs += __shfl_down(vs, off, 16);
                    vd += __shfl_down(vd, off, 16);
                }
                if ((t & 15) == 0) {
                    const int head = (t >> 4) & 1;
                    a_src[n * NHEAD + head] = vs;
                    a_dst[n * NHEAD + head] = vd;
                }
            }
        }
    }
}

// ---------------------------------------------------------------------------
// CSR build: degree histogram -> exclusive scan -> scatter src ids.
// Self loops are NOT stored; the agg kernel adds them inline.
// ---------------------------------------------------------------------------
__global__ void deg_kernel(const int* __restrict__ ei, int E, int* __restrict__ deg)
{
    int e = blockIdx.x * blockDim.x + threadIdx.x;
    if (e < E) atomicAdd(&deg[ei[E + e]], 1);
}

// single block, 1024 threads, shfl-based wave scan
__global__ void scan_kernel(const int* __restrict__ deg, int N,
                            int* __restrict__ rowptr, int* __restrict__ cursor)
{
    __shared__ int wsum[16];
    __shared__ int carry_s;
    const int t = threadIdx.x;
    const int lane = t & 63, w = t >> 6;
    if (t == 0) carry_s = 0;
    __syncthreads();
    for (int base = 0; base < N; base += 1024) {
        const int i = base + t;
        const int v = (i < N) ? deg[i] : 0;
        int s = v;
#pragma unroll
        for (int off = 1; off < 64; off <<= 1) {
            int u = __shfl_up(s, off);
            if (lane >= off) s += u;
        }
        if (lane == 63) wsum[w] = s;
        __syncthreads();
        if (w == 0 && lane < 16) {
            int ws = wsum[lane];
            int ss = ws;
#pragma unroll
            for (int off = 1; off < 16; off <<= 1) {
                int u = __shfl_up(ss, off);
                if (lane >= off) ss += u;
            }
            wsum[lane] = ss - ws;   // exclusive prefix of wave sums
        }
        __syncthreads();
        const int excl = carry_s + wsum[w] + s - v;
        if (i < N) { rowptr[i] = excl; cursor[i] = excl; }
        __syncthreads();
        if (t == 1023) carry_s += wsum[15] + s;
        __syncthreads();
    }
    if (t == 0) rowptr[N] = carry_s;
}

__global__ void scatter_kernel(const int* __restrict__ ei, int E,
                               int* __restrict__ cursor, int* __restrict__ col)
{
    int e = blockIdx.x * blockDim.x + threadIdx.x;
    if (e < E) {
        int d = ei[E + e];
        int p = atomicAdd(&cursor[d], 1);
        col[p] = ei[e];
    }
}

// ---------------------------------------------------------------------------
// Fused GAT aggregation + bias + (res) + LayerNorm + ELU + (skip).
// One block per dst node, thread t = channel. CSR gather, register acc.
// ---------------------------------------------------------------------------
__global__ void gat_agg_ln_kernel(const int* __restrict__ rowptr,
                                  const int* __restrict__ col,
                                  const float* __restrict__ H,
                                  const float* __restrict__ a_src,
                                  const float* __restrict__ a_dst,
                                  const float* __restrict__ bias,
                                  const float* __restrict__ res,    // nullable, pre-LN
                                  const float* __restrict__ lng,
                                  const float* __restrict__ lnb,
                                  const float* __restrict__ skip,   // nullable, post-ELU
                                  float* __restrict__ out)
{
    const int d = blockIdx.x, t = threadIdx.x;
    const int lane = t & 63, head = t >> 6;

    const float ad0 = a_dst[d * NHEAD + head];

    // self loop
    float e0 = a_src[d * NHEAD + head] + ad0;
    e0 = e0 > 0.f ? e0 : 0.2f * e0;
    float w = __expf(e0);
    float den = w;
    float acc = w * H[d * DM + t];

    int p = rowptr[d];
    const int p1 = rowptr[d + 1];
    for (; p + 1 < p1; p += 2) {
        int s0 = col[p], s1 = col[p + 1];
        float ea = a_src[s0 * NHEAD + head] + ad0;
        float eb = a_src[s1 * NHEAD + head] + ad0;
        float h0 = H[s0 * DM + t];
        float h1 = H[s1 * DM + t];
        ea = ea > 0.f ? ea : 0.2f * ea;
        eb = eb > 0.f ? eb : 0.2f * eb;
        float wa = __expf(ea), wb = __expf(eb);
        den += wa + wb;
        acc += wa * h0 + wb * h1;
    }
    if (p < p1) {
        int s0 = col[p];
        float ea = a_src[s0 * NHEAD + head] + ad0;
        float h0 = H[s0 * DM + t];
        ea = ea > 0.f ? ea : 0.2f * ea;
        float wa = __expf(ea);
        den += wa;
        acc += wa * h0;
    }

    const int i = d * DM + t;
    float v = acc / den + bias[t];
    if (res) v += res[i];

    __shared__ float red[2];
    float s = v;
#pragma unroll
    for (int off = 32; off; off >>= 1) s += __shfl_down(s, off);
    if (lane == 0) red[head] = s;
    __syncthreads();
    float mean = (red[0] + red[1]) * (1.f / DM);
    __syncthreads();

    float dv = v - mean;
    float s2 = dv * dv;
#pragma unroll
    for (int off = 32; off; off >>= 1) s2 += __shfl_down(s2, off);
    if (lane == 0) red[head] = s2;
    __syncthreads();
    float var = (red[0] + red[1]) * (1.f / DM);

    float y = dv * rsqrtf(var + EPS) * lng[t] + lnb[t];
    y = y > 0.f ? y : expm1f(y);   // ELU
    if (skip) y += skip[i];
    out[i] = y;
}

// ---------------------------------------------------------------------------
// Global mean pool: sorted batch -> per-block register runs, few atomics.
// ---------------------------------------------------------------------------
__global__ void pool_kernel(const float* __restrict__ emb,
                            const int* __restrict__ batch, int N,
                            float* __restrict__ sums,
                            float* __restrict__ cnt)
{
    const int t = threadIdx.x;
    const int chunk = (N + gridDim.x - 1) / gridDim.x;
    const int n0 = blockIdx.x * chunk;
    const int n1 = min(N, n0 + chunk);
    if (n0 >= n1) return;

    int cur = batch[n0];
    float acc = 0.f;
    int count = 0;
    for (int n = n0; n < n1; ++n) {
        int b = batch[n];
        if (b != cur) {
            atomicAdd(&sums[cur * DM + t], acc);
            if (t == 0) atomicAdd(&cnt[cur], (float)count);
            acc = 0.f; count = 0; cur = b;
        }
        acc += emb[n * DM + t];
        ++count;
    }
    atomicAdd(&sums[cur * DM + t], acc);
    if (t == 0) atomicAdd(&cnt[cur], (float)count);
}

// ---------------------------------------------------------------------------
// Head: graph_emb = sums/cnt; logits = ge @ Wfc + bfc; BatchNorm over graphs.
// ---------------------------------------------------------------------------
__global__ void head_kernel(const float* __restrict__ sums,
                            const float* __restrict__ cnt,
                            const float* __restrict__ Wfc,
                            const float* __restrict__ bfc,
                            const float* __restrict__ bn_g,
                            const float* __restrict__ bn_b,
                            float* __restrict__ out)
{
    __shared__ float ge[NG * DM];
    __shared__ float lg[NG * OUTC];
    __shared__ float mu[OUTC], inv[OUTC];
    const int t = threadIdx.x;

    for (int i = t; i < NG * DM; i += blockDim.x) {
        int g = i >> 7;
        ge[i] = sums[i] / fmaxf(cnt[g], 1.0f);
    }
    __syncthreads();

    for (int i = t; i < NG * OUTC; i += blockDim.x) {
        int g = i >> 5, o = i & (OUTC - 1);
        float acc = bfc[o];
#pragma unroll
        for (int k = 0; k < DM; ++k) acc += ge[g * DM + k] * Wfc[k * OUTC + o];
        lg[i] = acc;
    }
    __syncthreads();

    if (t < OUTC) {
        float s = 0.f;
        for (int g = 0; g < NG; ++g) s += lg[g * OUTC + t];
        float m = s * (1.f / NG);
        float v = 0.f;
        for (int g = 0; g < NG; ++g) { float d = lg[g * OUTC + t] - m; v += d * d; }
        v *= (1.f / NG);
        mu[t] = m;
        inv[t] = rsqrtf(v + EPS) * bn_g[t];
    }
    __syncthreads();

    for (int i = t; i < NG * OUTC; i += blockDim.x) {
        int o = i & (OUTC - 1);
        out[i] = (lg[i] - mu[o]) * inv[o] + bn_b[o];
    }
}

// ---------------------------------------------------------------------------
extern "C" void kernel_launch(void* const* d_in, const int* in_sizes, int n_in,
                              void* d_out, int out_size, void* d_ws, size_t ws_size,
                              hipStream_t stream)
{
    const float* x     = (const float*)d_in[0];
    const int*   ei    = (const int*)  d_in[1];
    const int*   batch = (const int*)  d_in[2];
    const float* W1    = (const float*)d_in[3];
    const float* as1   = (const float*)d_in[4];
    const float* ad1   = (const float*)d_in[5];
    const float* b1    = (const float*)d_in[6];
    const float* ln1g  = (const float*)d_in[7];
    const float* ln1b  = (const float*)d_in[8];
    const float* Wskip = (const float*)d_in[9];
    const float* bskip = (const float*)d_in[10];
    const float* W2    = (const float*)d_in[11];
    const float* as2   = (const float*)d_in[12];
    const float* ad2   = (const float*)d_in[13];
    const float* b2    = (const float*)d_in[14];
    const float* ln2g  = (const float*)d_in[15];
    const float* ln2b  = (const float*)d_in[16];
    const float* Wfc   = (const float*)d_in[17];
    const float* bfc   = (const float*)d_in[18];
    const float* bng   = (const float*)d_in[19];
    const float* bnb   = (const float*)d_in[20];

    const int N  = in_sizes[2];
    const int E  = in_sizes[1] / 2;

    size_t off = 0;
    auto alloc = [&](size_t bytes) -> char* {
        char* p = (char*)d_ws + off;
        off += (bytes + 255) & ~(size_t)255;
        return p;
    };
    float* Hbuf   = (float*)alloc((size_t)N * DM * 4);   // h1, then h2
    float* Buf1   = (float*)alloc((size_t)N * DM * 4);   // x1 (kept for residual)
    float* Buf2   = (float*)alloc((size_t)N * DM * 4);   // skip -> emb
    float* asrc   = (float*)alloc((size_t)N * NHEAD * 4);
    float* adst   = (float*)alloc((size_t)N * NHEAD * 4);
    int*   deg    = (int*)  alloc((size_t)N * 4);
    int*   rowptr = (int*)  alloc((size_t)(N + 1) * 4);
    int*   cursor = (int*)  alloc((size_t)N * 4);
    int*   col    = (int*)  alloc((size_t)E * 4);
    float* sums   = (float*)alloc((size_t)(NG * DM + NG) * 4);
    float* cnt    = sums + NG * DM;

    const int eb = (E + 255) / 256;
    const int gb = (N + TM - 1) / TM;

    // ---- CSR build (shared by both layers) ----
    hipMemsetAsync(deg, 0, (size_t)N * 4, stream);
    deg_kernel<<<eb, 256, 0, stream>>>(ei, E, deg);
    scan_kernel<<<1, 1024, 0, stream>>>(deg, N, rowptr, cursor);
    scatter_kernel<<<eb, 256, 0, stream>>>(ei, E, cursor, col);

    // ---- layer 1 ----
    gemm_tile_kernel<<<gb, 256, 0, stream>>>(x, N, W1, nullptr, as1, ad1,
                                             Hbuf, asrc, adst);
    gemm_tile_kernel<<<gb, 256, 0, stream>>>(x, N, Wskip, bskip, nullptr, nullptr,
                                             Buf2, nullptr, nullptr);
    gat_agg_ln_kernel<<<N, DM, 0, stream>>>(rowptr, col, Hbuf, asrc, adst,
                                            b1, nullptr, ln1g, ln1b, Buf2, Buf1);

    // ---- layer 2 ----
    gemm_tile_kernel<<<gb, 256, 0, stream>>>(Buf1, N, W2, nullptr, as2, ad2,
                                             Hbuf, asrc, adst);
    gat_agg_ln_kernel<<<N, DM, 0, stream>>>(rowptr, col, Hbuf, asrc, adst,
                                            b2, Buf1, ln2g, ln2b, nullptr, Buf2);

    // ---- pool + head ----
    hipMemsetAsync(sums, 0, (size_t)(NG * DM + NG) * 4, stream);
    pool_kernel<<<1024, DM, 0, stream>>>(Buf2, batch, N, sums, cnt);
    head_kernel<<<1, 1024, 0, stream>>>(sums, cnt, Wfc, bfc, bng, bnb, (float*)d_out);
}

// Round 7
// 452.460 us; speedup vs baseline: 7.3834x; 1.0305x over previous
//
#include <hip/hip_runtime.h>

#define DM    128
#define NHEAD 2
#define HIDC  64
#define OUTC  32
#define NG    64
#define EPS   1e-5f
#define TM    32     // rows per GEMM block

__device__ __forceinline__ unsigned short f2bf(float f) {
    union { float f; unsigned int u; } v; v.f = f;
    unsigned int r = v.u + 0x7fffu + ((v.u >> 16) & 1u);   // RNE
    return (unsigned short)(r >> 16);
}
__device__ __forceinline__ float bf2f(unsigned short h) {
    union { unsigned int u; float f; } v; v.u = ((unsigned int)h) << 16;
    return v.f;
}

// ---------------------------------------------------------------------------
// Tiled GEMM: C[n0..n0+TM) x [0..128) = X-chunk @ W  (+bias) (+att dots).
// W (64 KB) + X chunk (16 KB) staged in LDS -> 80 KB, 2 blocks/CU.
// 256 threads; thread t owns 4 rows x 4 cols. Output: fp32 (C) or bf16 (Cbf).
// ---------------------------------------------------------------------------
__global__ __launch_bounds__(256) void gemm_tile_kernel(
    const float* __restrict__ X, int N,
    const float* __restrict__ W,
    const float* __restrict__ bias,      // nullable
    const float* __restrict__ att_src,   // nullable (with att_dst)
    const float* __restrict__ att_dst,
    float* __restrict__ C,               // nullable (then Cbf used)
    unsigned short* __restrict__ Cbf,    // nullable
    float* __restrict__ a_src,
    float* __restrict__ a_dst)
{
    __shared__ float Ws[DM * DM];        // 64 KB
    __shared__ float Xs[TM * DM];        // 16 KB
    const int t  = threadIdx.x;
    const int n0 = blockIdx.x * TM;

    // stage W: 16384 floats = 4096 float4, 16 per thread
    {
        const float4* Wv  = (const float4*)W;
        float4*       Wsv = (float4*)Ws;
#pragma unroll
        for (int i = 0; i < 16; ++i)
            Wsv[t + i * 256] = Wv[t + i * 256];
    }
    // stage X chunk: 4096 floats = 1024 float4 = 4 float4/thread
    {
#pragma unroll
        for (int i = 0; i < 4; ++i) {
            const int idx = (t + i * 256) * 4;
            const int n = n0 + (idx >> 7);
            float4 v = make_float4(0.f, 0.f, 0.f, 0.f);
            if (n < N) v = *(const float4*)&X[n * DM + (idx & 127)];
            *(float4*)&Xs[idx] = v;
        }
    }
    __syncthreads();

    const int c4 = (t & 31) * 4;
    const int r0 = (t >> 5) * 4;

    float acc[4][4];
#pragma unroll
    for (int i = 0; i < 4; ++i)
#pragma unroll
        for (int j = 0; j < 4; ++j) acc[i][j] = 0.f;

#pragma unroll 4
    for (int k = 0; k < DM; ++k) {
        const float4 wv = *(const float4*)&Ws[k * DM + c4];
        const float x0 = Xs[(r0 + 0) * DM + k];
        const float x1 = Xs[(r0 + 1) * DM + k];
        const float x2 = Xs[(r0 + 2) * DM + k];
        const float x3 = Xs[(r0 + 3) * DM + k];
        acc[0][0] += x0 * wv.x; acc[0][1] += x0 * wv.y; acc[0][2] += x0 * wv.z; acc[0][3] += x0 * wv.w;
        acc[1][0] += x1 * wv.x; acc[1][1] += x1 * wv.y; acc[1][2] += x1 * wv.z; acc[1][3] += x1 * wv.w;
        acc[2][0] += x2 * wv.x; acc[2][1] += x2 * wv.y; acc[2][2] += x2 * wv.z; acc[2][3] += x2 * wv.w;
        acc[3][0] += x3 * wv.x; acc[3][1] += x3 * wv.y; acc[3][2] += x3 * wv.z; acc[3][3] += x3 * wv.w;
    }

    if (bias) {
        const float4 bv = *(const float4*)&bias[c4];
#pragma unroll
        for (int i = 0; i < 4; ++i) {
            acc[i][0] += bv.x; acc[i][1] += bv.y; acc[i][2] += bv.z; acc[i][3] += bv.w;
        }
    }

    float4 avs, avd;
    if (att_src) {
        avs = *(const float4*)&att_src[c4];
        avd = *(const float4*)&att_dst[c4];
    }

#pragma unroll
    for (int i = 0; i < 4; ++i) {
        const int n = n0 + r0 + i;
        if (n < N) {
            float4 o = make_float4(acc[i][0], acc[i][1], acc[i][2], acc[i][3]);
            if (Cbf) {
                ushort4 ob;
                ob.x = f2bf(o.x); ob.y = f2bf(o.y); ob.z = f2bf(o.z); ob.w = f2bf(o.w);
                *(ushort4*)&Cbf[n * DM + c4] = ob;
            } else {
                *(float4*)&C[n * DM + c4] = o;
            }
            if (att_src) {   // dots from fp32 values (pre-rounding)
                float vs = o.x * avs.x + o.y * avs.y + o.z * avs.z + o.w * avs.w;
                float vd = o.x * avd.x + o.y * avd.y + o.z * avd.z + o.w * avd.w;
#pragma unroll
                for (int off = 8; off; off >>= 1) {
                    vs += __shfl_down(vs, off, 16);
                    vd += __shfl_down(vd, off, 16);
                }
                if ((t & 15) == 0) {
                    const int head = (t >> 4) & 1;
                    a_src[n * NHEAD + head] = vs;
                    a_dst[n * NHEAD + head] = vd;
                }
            }
        }
    }
}

// ---------------------------------------------------------------------------
// CSR build: degree histogram -> exclusive scan -> scatter src ids.
// ---------------------------------------------------------------------------
__global__ void deg_kernel(const int* __restrict__ ei, int E, int* __restrict__ deg)
{
    int e = blockIdx.x * blockDim.x + threadIdx.x;
    if (e < E) atomicAdd(&deg[ei[E + e]], 1);
}

__global__ void scan_kernel(const int* __restrict__ deg, int N,
                            int* __restrict__ rowptr, int* __restrict__ cursor)
{
    __shared__ int wsum[16];
    __shared__ int carry_s;
    const int t = threadIdx.x;
    const int lane = t & 63, w = t >> 6;
    if (t == 0) carry_s = 0;
    __syncthreads();
    for (int base = 0; base < N; base += 1024) {
        const int i = base + t;
        const int v = (i < N) ? deg[i] : 0;
        int s = v;
#pragma unroll
        for (int off = 1; off < 64; off <<= 1) {
            int u = __shfl_up(s, off);
            if (lane >= off) s += u;
        }
        if (lane == 63) wsum[w] = s;
        __syncthreads();
        if (w == 0 && lane < 16) {
            int ws = wsum[lane];
            int ss = ws;
#pragma unroll
            for (int off = 1; off < 16; off <<= 1) {
                int u = __shfl_up(ss, off);
                if (lane >= off) ss += u;
            }
            wsum[lane] = ss - ws;
        }
        __syncthreads();
        const int excl = carry_s + wsum[w] + s - v;
        if (i < N) { rowptr[i] = excl; cursor[i] = excl; }
        __syncthreads();
        if (t == 1023) carry_s += wsum[15] + s;
        __syncthreads();
    }
    if (t == 0) rowptr[N] = carry_s;
}

__global__ void scatter_kernel(const int* __restrict__ ei, int E,
                               int* __restrict__ cursor, int* __restrict__ col)
{
    int e = blockIdx.x * blockDim.x + threadIdx.x;
    if (e < E) {
        int d = ei[E + e];
        int p = atomicAdd(&cursor[d], 1);
        col[p] = ei[e];
    }
}

// ---------------------------------------------------------------------------
// Fused GAT aggregation + bias + (res) + LayerNorm + ELU + (skip).
// One block (128 thr) per dst node. Per 64-edge chunk:
//   phase A: lane l computes edge l's weight (exp once per edge per head)
//            into LDS; butterfly-reduce denominator.
//   phase B: all threads gather-FMA bf16 H rows with broadcast LDS weights.
// ---------------------------------------------------------------------------
__global__ __launch_bounds__(128) void gat_agg_ln_kernel(
    const int* __restrict__ rowptr,
    const int* __restrict__ col,
    const unsigned short* __restrict__ H,   // bf16
    const float* __restrict__ a_src,
    const float* __restrict__ a_dst,
    const float* __restrict__ bias,
    const float* __restrict__ res,    // nullable, pre-LN
    const float* __restrict__ lng,
    const float* __restrict__ lnb,
    const float* __restrict__ skip,   // nullable, post-ELU
    float* __restrict__ out)
{
    const int d = blockIdx.x, t = threadIdx.x;
    const int lane = t & 63, head = t >> 6;

    __shared__ int   sbuf[64];
    __shared__ float wbuf[2][64];
    __shared__ float red[2];

    const float ad0 = a_dst[d * NHEAD + head];

    // self loop
    float e0 = a_src[d * NHEAD + head] + ad0;
    e0 = e0 > 0.f ? e0 : 0.2f * e0;
    const float wself = __expf(e0);
    float den = wself;
    float acc = wself * bf2f(H[d * DM + t]);

    const int p0 = rowptr[d], p1 = rowptr[d + 1];
    for (int base = p0; base < p1; base += 64) {
        const int m = min(64, p1 - base);

        // phase A: one lane per edge computes the weight for its head
        float we = 0.f;
        if (lane < m) {
            const int s = col[base + lane];
            if (head == 0) sbuf[lane] = s;
            float e = a_src[s * NHEAD + head] + ad0;
            e = e > 0.f ? e : 0.2f * e;
            we = __expf(e);
            wbuf[head][lane] = we;
        }
        float ws = we;
#pragma unroll
        for (int off = 32; off; off >>= 1) ws += __shfl_xor(ws, off);
        den += ws;
        __syncthreads();

        // phase B: gather-FMA (weights/srcs broadcast from LDS)
        const int e2 = m & ~1;
        for (int e = 0; e < e2; e += 2) {
            const int s0 = sbuf[e], s1 = sbuf[e + 1];
            const float w0 = wbuf[head][e], w1 = wbuf[head][e + 1];
            const float h0 = bf2f(H[s0 * DM + t]);
            const float h1 = bf2f(H[s1 * DM + t]);
            acc += w0 * h0 + w1 * h1;
        }
        if (e2 < m)
            acc += wbuf[head][e2] * bf2f(H[sbuf[e2] * DM + t]);
        __syncthreads();   // before next chunk overwrites sbuf/wbuf
    }

    const int i = d * DM + t;
    float v = acc / den + bias[t];
    if (res) v += res[i];

    float s = v;
#pragma unroll
    for (int off = 32; off; off >>= 1) s += __shfl_down(s, off);
    if (lane == 0) red[head] = s;
    __syncthreads();
    float mean = (red[0] + red[1]) * (1.f / DM);
    __syncthreads();

    float dv = v - mean;
    float s2 = dv * dv;
#pragma unroll
    for (int off = 32; off; off >>= 1) s2 += __shfl_down(s2, off);
    if (lane == 0) red[head] = s2;
    __syncthreads();
    float var = (red[0] + red[1]) * (1.f / DM);

    float y = dv * rsqrtf(var + EPS) * lng[t] + lnb[t];
    y = y > 0.f ? y : expm1f(y);   // ELU
    if (skip) y += skip[i];
    out[i] = y;
}

// ---------------------------------------------------------------------------
// Global mean pool: sorted batch -> per-block register runs, few atomics.
// ---------------------------------------------------------------------------
__global__ void pool_kernel(const float* __restrict__ emb,
                            const int* __restrict__ batch, int N,
                            float* __restrict__ sums,
                            float* __restrict__ cnt)
{
    const int t = threadIdx.x;
    const int chunk = (N + gridDim.x - 1) / gridDim.x;
    const int n0 = blockIdx.x * chunk;
    const int n1 = min(N, n0 + chunk);
    if (n0 >= n1) return;

    int cur = batch[n0];
    float acc = 0.f;
    int count = 0;
    for (int n = n0; n < n1; ++n) {
        int b = batch[n];
        if (b != cur) {
            atomicAdd(&sums[cur * DM + t], acc);
            if (t == 0) atomicAdd(&cnt[cur], (float)count);
            acc = 0.f; count = 0; cur = b;
        }
        acc += emb[n * DM + t];
        ++count;
    }
    atomicAdd(&sums[cur * DM + t], acc);
    if (t == 0) atomicAdd(&cnt[cur], (float)count);
}

// ---------------------------------------------------------------------------
// Head: graph_emb = sums/cnt; logits = ge @ Wfc + bfc; BatchNorm over graphs.
// ---------------------------------------------------------------------------
__global__ void head_kernel(const float* __restrict__ sums,
                            const float* __restrict__ cnt,
                            const float* __restrict__ Wfc,
                            const float* __restrict__ bfc,
                            const float* __restrict__ bn_g,
                            const float* __restrict__ bn_b,
                            float* __restrict__ out)
{
    __shared__ float ge[NG * DM];
    __shared__ float lg[NG * OUTC];
    __shared__ float mu[OUTC], inv[OUTC];
    const int t = threadIdx.x;

    for (int i = t; i < NG * DM; i += blockDim.x) {
        int g = i >> 7;
        ge[i] = sums[i] / fmaxf(cnt[g], 1.0f);
    }
    __syncthreads();

    for (int i = t; i < NG * OUTC; i += blockDim.x) {
        int g = i >> 5, o = i & (OUTC - 1);
        float acc = bfc[o];
#pragma unroll
        for (int k = 0; k < DM; ++k) acc += ge[g * DM + k] * Wfc[k * OUTC + o];
        lg[i] = acc;
    }
    __syncthreads();

    if (t < OUTC) {
        float s = 0.f;
        for (int g = 0; g < NG; ++g) s += lg[g * OUTC + t];
        float m = s * (1.f / NG);
        float v = 0.f;
        for (int g = 0; g < NG; ++g) { float d = lg[g * OUTC + t] - m; v += d * d; }
        v *= (1.f / NG);
        mu[t] = m;
        inv[t] = rsqrtf(v + EPS) * bn_g[t];
    }
    __syncthreads();

    for (int i = t; i < NG * OUTC; i += blockDim.x) {
        int o = i & (OUTC - 1);
        out[i] = (lg[i] - mu[o]) * inv[o] + bn_b[o];
    }
}

// ---------------------------------------------------------------------------
extern "C" void kernel_launch(void* const* d_in, const int* in_sizes, int n_in,
                              void* d_out, int out_size, void* d_ws, size_t ws_size,
                              hipStream_t stream)
{
    const float* x     = (const float*)d_in[0];
    const int*   ei    = (const int*)  d_in[1];
    const int*   batch = (const int*)  d_in[2];
    const float* W1    = (const float*)d_in[3];
    const float* as1   = (const float*)d_in[4];
    const float* ad1   = (const float*)d_in[5];
    const float* b1    = (const float*)d_in[6];
    const float* ln1g  = (const float*)d_in[7];
    const float* ln1b  = (const float*)d_in[8];
    const float* Wskip = (const float*)d_in[9];
    const float* bskip = (const float*)d_in[10];
    const float* W2    = (const float*)d_in[11];
    const float* as2   = (const float*)d_in[12];
    const float* ad2   = (const float*)d_in[13];
    const float* b2    = (const float*)d_in[14];
    const float* ln2g  = (const float*)d_in[15];
    const float* ln2b  = (const float*)d_in[16];
    const float* Wfc   = (const float*)d_in[17];
    const float* bfc   = (const float*)d_in[18];
    const float* bng   = (const float*)d_in[19];
    const float* bnb   = (const float*)d_in[20];

    const int N  = in_sizes[2];
    const int E  = in_sizes[1] / 2;

    size_t off = 0;
    auto alloc = [&](size_t bytes) -> char* {
        char* p = (char*)d_ws + off;
        off += (bytes + 255) & ~(size_t)255;
        return p;
    };
    unsigned short* Hbuf = (unsigned short*)alloc((size_t)N * DM * 2);  // bf16 h1/h2
    float* Buf1   = (float*)alloc((size_t)N * DM * 4);   // x1 (kept for residual)
    float* Buf2   = (float*)alloc((size_t)N * DM * 4);   // skip -> emb
    float* asrc   = (float*)alloc((size_t)N * NHEAD * 4);
    float* adst   = (float*)alloc((size_t)N * NHEAD * 4);
    int*   deg    = (int*)  alloc((size_t)N * 4);
    int*   rowptr = (int*)  alloc((size_t)(N + 1) * 4);
    int*   cursor = (int*)  alloc((size_t)N * 4);
    int*   col    = (int*)  alloc((size_t)E * 4);
    float* sums   = (float*)alloc((size_t)(NG * DM + NG) * 4);
    float* cnt    = sums + NG * DM;

    const int eb = (E + 255) / 256;
    const int gb = (N + TM - 1) / TM;

    // ---- CSR build (shared by both layers) ----
    hipMemsetAsync(deg, 0, (size_t)N * 4, stream);
    deg_kernel<<<eb, 256, 0, stream>>>(ei, E, deg);
    scan_kernel<<<1, 1024, 0, stream>>>(deg, N, rowptr, cursor);
    scatter_kernel<<<eb, 256, 0, stream>>>(ei, E, cursor, col);

    // ---- layer 1 ----
    gemm_tile_kernel<<<gb, 256, 0, stream>>>(x, N, W1, nullptr, as1, ad1,
                                             nullptr, Hbuf, asrc, adst);
    gemm_tile_kernel<<<gb, 256, 0, stream>>>(x, N, Wskip, bskip, nullptr, nullptr,
                                             Buf2, nullptr, nullptr, nullptr);
    gat_agg_ln_kernel<<<N, DM, 0, stream>>>(rowptr, col, Hbuf, asrc, adst,
                                            b1, nullptr, ln1g, ln1b, Buf2, Buf1);

    // ---- layer 2 ----
    gemm_tile_kernel<<<gb, 256, 0, stream>>>(Buf1, N, W2, nullptr, as2, ad2,
                                             nullptr, Hbuf, asrc, adst);
    gat_agg_ln_kernel<<<N, DM, 0, stream>>>(rowptr, col, Hbuf, asrc, adst,
                                            b2, Buf1, ln2g, ln2b, nullptr, Buf2);

    // ---- pool + head ----
    hipMemsetAsync(sums, 0, (size_t)(NG * DM + NG) * 4, stream);
    pool_kernel<<<1024, DM, 0, stream>>>(Buf2, batch, N, sums, cnt);
    head_kernel<<<1, 1024, 0, stream>>>(sums, cnt, Wfc, bfc, bng, bnb, (float*)d_out);
}

// Round 8
// 392.021 us; speedup vs baseline: 8.5218x; 1.1542x over previous
//
#include <hip/hip_runtime.h>

#define DM    128
#define NHEAD 2
#define HIDC  64
#define OUTC  32
#define NG    64
#define EPS   1e-5f
#define TM    32     // rows per GEMM block

__device__ __forceinline__ unsigned short f2bf(float f) {
    union { float f; unsigned int u; } v; v.f = f;
    unsigned int r = v.u + 0x7fffu + ((v.u >> 16) & 1u);   // RNE
    return (unsigned short)(r >> 16);
}
__device__ __forceinline__ float bf2f(unsigned short h) {
    union { unsigned int u; float f; } v; v.u = ((unsigned int)h) << 16;
    return v.f;
}
__device__ __forceinline__ float bflo(unsigned int u) {
    union { unsigned int u; float f; } v; v.u = u << 16; return v.f;
}
__device__ __forceinline__ float bfhi(unsigned int u) {
    union { unsigned int u; float f; } v; v.u = u & 0xffff0000u; return v.f;
}

// ---------------------------------------------------------------------------
// Tiled GEMM: C[n0..n0+TM) x [0..128) = X-chunk @ W  (+bias) (+att dots).
// W (64 KB) + X chunk (16 KB) staged in LDS -> 80 KB, 2 blocks/CU.
// 256 threads; thread t owns 4 rows x 4 cols. Output: fp32 (C) or bf16 (Cbf).
// ---------------------------------------------------------------------------
__global__ __launch_bounds__(256) void gemm_tile_kernel(
    const float* __restrict__ X, int N,
    const float* __restrict__ W,
    const float* __restrict__ bias,      // nullable
    const float* __restrict__ att_src,   // nullable (with att_dst)
    const float* __restrict__ att_dst,
    float* __restrict__ C,               // nullable (then Cbf used)
    unsigned short* __restrict__ Cbf,    // nullable
    float* __restrict__ a_src,
    float* __restrict__ a_dst)
{
    __shared__ float Ws[DM * DM];        // 64 KB
    __shared__ float Xs[TM * DM];        // 16 KB
    const int t  = threadIdx.x;
    const int n0 = blockIdx.x * TM;

    // stage W: 16384 floats = 4096 float4, 16 per thread
    {
        const float4* Wv  = (const float4*)W;
        float4*       Wsv = (float4*)Ws;
#pragma unroll
        for (int i = 0; i < 16; ++i)
            Wsv[t + i * 256] = Wv[t + i * 256];
    }
    // stage X chunk: 4096 floats = 1024 float4 = 4 float4/thread
    {
#pragma unroll
        for (int i = 0; i < 4; ++i) {
            const int idx = (t + i * 256) * 4;
            const int n = n0 + (idx >> 7);
            float4 v = make_float4(0.f, 0.f, 0.f, 0.f);
            if (n < N) v = *(const float4*)&X[n * DM + (idx & 127)];
            *(float4*)&Xs[idx] = v;
        }
    }
    __syncthreads();

    const int c4 = (t & 31) * 4;
    const int r0 = (t >> 5) * 4;

    float acc[4][4];
#pragma unroll
    for (int i = 0; i < 4; ++i)
#pragma unroll
        for (int j = 0; j < 4; ++j) acc[i][j] = 0.f;

#pragma unroll 4
    for (int k = 0; k < DM; ++k) {
        const float4 wv = *(const float4*)&Ws[k * DM + c4];
        const float x0 = Xs[(r0 + 0) * DM + k];
        const float x1 = Xs[(r0 + 1) * DM + k];
        const float x2 = Xs[(r0 + 2) * DM + k];
        const float x3 = Xs[(r0 + 3) * DM + k];
        acc[0][0] += x0 * wv.x; acc[0][1] += x0 * wv.y; acc[0][2] += x0 * wv.z; acc[0][3] += x0 * wv.w;
        acc[1][0] += x1 * wv.x; acc[1][1] += x1 * wv.y; acc[1][2] += x1 * wv.z; acc[1][3] += x1 * wv.w;
        acc[2][0] += x2 * wv.x; acc[2][1] += x2 * wv.y; acc[2][2] += x2 * wv.z; acc[2][3] += x2 * wv.w;
        acc[3][0] += x3 * wv.x; acc[3][1] += x3 * wv.y; acc[3][2] += x3 * wv.z; acc[3][3] += x3 * wv.w;
    }

    if (bias) {
        const float4 bv = *(const float4*)&bias[c4];
#pragma unroll
        for (int i = 0; i < 4; ++i) {
            acc[i][0] += bv.x; acc[i][1] += bv.y; acc[i][2] += bv.z; acc[i][3] += bv.w;
        }
    }

    float4 avs, avd;
    if (att_src) {
        avs = *(const float4*)&att_src[c4];
        avd = *(const float4*)&att_dst[c4];
    }

#pragma unroll
    for (int i = 0; i < 4; ++i) {
        const int n = n0 + r0 + i;
        if (n < N) {
            float4 o = make_float4(acc[i][0], acc[i][1], acc[i][2], acc[i][3]);
            if (Cbf) {
                ushort4 ob;
                ob.x = f2bf(o.x); ob.y = f2bf(o.y); ob.z = f2bf(o.z); ob.w = f2bf(o.w);
                *(ushort4*)&Cbf[n * DM + c4] = ob;
            } else {
                *(float4*)&C[n * DM + c4] = o;
            }
            if (att_src) {   // dots from fp32 values (pre-rounding)
                float vs = o.x * avs.x + o.y * avs.y + o.z * avs.z + o.w * avs.w;
                float vd = o.x * avd.x + o.y * avd.y + o.z * avd.z + o.w * avd.w;
#pragma unroll
                for (int off = 8; off; off >>= 1) {
                    vs += __shfl_down(vs, off, 16);
                    vd += __shfl_down(vd, off, 16);
                }
                if ((t & 15) == 0) {
                    const int head = (t >> 4) & 1;
                    a_src[n * NHEAD + head] = vs;
                    a_dst[n * NHEAD + head] = vd;
                }
            }
        }
    }
}

// ---------------------------------------------------------------------------
// CSR build: degree histogram -> exclusive scan -> scatter src ids.
// ---------------------------------------------------------------------------
__global__ void deg_kernel(const int* __restrict__ ei, int E, int* __restrict__ deg)
{
    int e = blockIdx.x * blockDim.x + threadIdx.x;
    if (e < E) atomicAdd(&deg[ei[E + e]], 1);
}

__global__ void scan_kernel(const int* __restrict__ deg, int N,
                            int* __restrict__ rowptr, int* __restrict__ cursor)
{
    __shared__ int wsum[16];
    __shared__ int carry_s;
    const int t = threadIdx.x;
    const int lane = t & 63, w = t >> 6;
    if (t == 0) carry_s = 0;
    __syncthreads();
    for (int base = 0; base < N; base += 1024) {
        const int i = base + t;
        const int v = (i < N) ? deg[i] : 0;
        int s = v;
#pragma unroll
        for (int off = 1; off < 64; off <<= 1) {
            int u = __shfl_up(s, off);
            if (lane >= off) s += u;
        }
        if (lane == 63) wsum[w] = s;
        __syncthreads();
        if (w == 0 && lane < 16) {
            int ws = wsum[lane];
            int ss = ws;
#pragma unroll
            for (int off = 1; off < 16; off <<= 1) {
                int u = __shfl_up(ss, off);
                if (lane >= off) ss += u;
            }
            wsum[lane] = ss - ws;
        }
        __syncthreads();
        const int excl = carry_s + wsum[w] + s - v;
        if (i < N) { rowptr[i] = excl; cursor[i] = excl; }
        __syncthreads();
        if (t == 1023) carry_s += wsum[15] + s;
        __syncthreads();
    }
    if (t == 0) rowptr[N] = carry_s;
}

__global__ void scatter_kernel(const int* __restrict__ ei, int E,
                               int* __restrict__ cursor, int* __restrict__ col)
{
    int e = blockIdx.x * blockDim.x + threadIdx.x;
    if (e < E) {
        int d = ei[E + e];
        int p = atomicAdd(&cursor[d], 1);
        col[p] = ei[e];
    }
}

// ---------------------------------------------------------------------------
// Fused GAT aggregation + bias + (res) + LayerNorm + ELU + (skip).
// ONE WAVE per dst node (2 nodes per 128-thread block), 2 channels/thread
// via u32 loads (64 lanes x 4B = full 256B bf16 row in one instruction).
// No LDS, no barriers: per 32-edge chunk, lane l computes edge (l&31)'s
// weight for head (l>>5); denominator via intra-half shfl_xor butterfly;
// FMA loop broadcasts src id / weight via __shfl; 4-edge unroll for MLP.
// ---------------------------------------------------------------------------
__global__ __launch_bounds__(128) void gat_agg_ln_kernel(
    const int* __restrict__ rowptr,
    const int* __restrict__ col,
    const unsigned short* __restrict__ H,   // bf16
    const float* __restrict__ a_src,
    const float* __restrict__ a_dst,
    const float* __restrict__ bias,
    const float* __restrict__ res,    // nullable, pre-LN
    const float* __restrict__ lng,
    const float* __restrict__ lnb,
    const float* __restrict__ skip,   // nullable, post-ELU
    float* __restrict__ out, int N)
{
    const int wid  = threadIdx.x >> 6;
    const int d    = blockIdx.x * 2 + wid;
    if (d >= N) return;
    const int lane = threadIdx.x & 63;
    const int half = lane >> 5;          // head of this thread's channels AND
                                         // head this lane computes weights for
    const int c2   = lane * 2;           // channel pair base

    const float ad_h = a_dst[d * NHEAD + half];

    // self loop
    float e0 = a_src[d * NHEAD + half] + ad_h;
    e0 = e0 > 0.f ? e0 : 0.2f * e0;
    const float wself = __expf(e0);
    float den = wself;
    float2 acc;
    {
        const unsigned int hu = *(const unsigned int*)&H[d * DM + c2];
        acc.x = wself * bflo(hu);
        acc.y = wself * bfhi(hu);
    }

    const int p0 = rowptr[d], p1 = rowptr[d + 1];
    for (int base = p0; base < p1; base += 32) {
        const int m = min(32, p1 - base);
        const int el = lane & 31;

        // phase A: weight for edge el, head `half` (one exp per lane)
        float we = 0.f;
        int s = 0;
        if (el < m) {
            s = col[base + el];
            float a = a_src[s * NHEAD + half] + ad_h;
            a = a > 0.f ? a : 0.2f * a;
            we = __expf(a);
        }
        // denominator: butterfly within each 32-lane half
        float ws = we;
#pragma unroll
        for (int off = 1; off < 32; off <<= 1) ws += __shfl_xor(ws, off);
        den += ws;

        // phase B: gather-FMA, broadcast s/we via shuffles, 4-edge unroll
        const int hsel = lane & 32;      // my head's weight lives at lane hsel|e
        int e = 0;
        for (; e + 4 <= m; e += 4) {
            const int s0 = __shfl(s, e),     s1 = __shfl(s, e + 1);
            const int s2 = __shfl(s, e + 2), s3 = __shfl(s, e + 3);
            const float w0 = __shfl(we, hsel | e),       w1 = __shfl(we, hsel | (e + 1));
            const float w2 = __shfl(we, hsel | (e + 2)), w3 = __shfl(we, hsel | (e + 3));
            const unsigned int u0 = *(const unsigned int*)&H[s0 * DM + c2];
            const unsigned int u1 = *(const unsigned int*)&H[s1 * DM + c2];
            const unsigned int u2 = *(const unsigned int*)&H[s2 * DM + c2];
            const unsigned int u3 = *(const unsigned int*)&H[s3 * DM + c2];
            acc.x += w0 * bflo(u0) + w1 * bflo(u1) + w2 * bflo(u2) + w3 * bflo(u3);
            acc.y += w0 * bfhi(u0) + w1 * bfhi(u1) + w2 * bfhi(u2) + w3 * bfhi(u3);
        }
        for (; e < m; ++e) {
            const int sE = __shfl(s, e);
            const float wE = __shfl(we, hsel | e);
            const unsigned int uE = *(const unsigned int*)&H[sE * DM + c2];
            acc.x += wE * bflo(uE);
            acc.y += wE * bfhi(uE);
        }
    }

    const int ibase = d * DM + c2;
    const float2 bv = *(const float2*)&bias[c2];
    float vx = acc.x / den + bv.x;
    float vy = acc.y / den + bv.y;
    if (res) {
        const float2 r = *(const float2*)&res[ibase];
        vx += r.x; vy += r.y;
    }

    // LayerNorm over 128 channels, fully within the wave (float2/thread)
    float sm = vx + vy;
#pragma unroll
    for (int off = 1; off < 64; off <<= 1) sm += __shfl_xor(sm, off);
    const float mean = sm * (1.f / DM);

    const float dx = vx - mean, dy = vy - mean;
    float s2 = dx * dx + dy * dy;
#pragma unroll
    for (int off = 1; off < 64; off <<= 1) s2 += __shfl_xor(s2, off);
    const float rstd = rsqrtf(s2 * (1.f / DM) + EPS);

    const float2 gv = *(const float2*)&lng[c2];
    const float2 bb = *(const float2*)&lnb[c2];
    float yx = dx * rstd * gv.x + bb.x;
    float yy = dy * rstd * gv.y + bb.y;
    yx = yx > 0.f ? yx : expm1f(yx);
    yy = yy > 0.f ? yy : expm1f(yy);
    if (skip) {
        const float2 sk = *(const float2*)&skip[ibase];
        yx += sk.x; yy += sk.y;
    }
    *(float2*)&out[ibase] = make_float2(yx, yy);
}

// ---------------------------------------------------------------------------
// Global mean pool: sorted batch -> per-block register runs, few atomics.
// ---------------------------------------------------------------------------
__global__ void pool_kernel(const float* __restrict__ emb,
                            const int* __restrict__ batch, int N,
                            float* __restrict__ sums,
                            float* __restrict__ cnt)
{
    const int t = threadIdx.x;
    const int chunk = (N + gridDim.x - 1) / gridDim.x;
    const int n0 = blockIdx.x * chunk;
    const int n1 = min(N, n0 + chunk);
    if (n0 >= n1) return;

    int cur = batch[n0];
    float acc = 0.f;
    int count = 0;
    for (int n = n0; n < n1; ++n) {
        int b = batch[n];
        if (b != cur) {
            atomicAdd(&sums[cur * DM + t], acc);
            if (t == 0) atomicAdd(&cnt[cur], (float)count);
            acc = 0.f; count = 0; cur = b;
        }
        acc += emb[n * DM + t];
        ++count;
    }
    atomicAdd(&sums[cur * DM + t], acc);
    if (t == 0) atomicAdd(&cnt[cur], (float)count);
}

// ---------------------------------------------------------------------------
// Head: graph_emb = sums/cnt; logits = ge @ Wfc + bfc; BatchNorm over graphs.
// ---------------------------------------------------------------------------
__global__ void head_kernel(const float* __restrict__ sums,
                            const float* __restrict__ cnt,
                            const float* __restrict__ Wfc,
                            const float* __restrict__ bfc,
                            const float* __restrict__ bn_g,
                            const float* __restrict__ bn_b,
                            float* __restrict__ out)
{
    __shared__ float ge[NG * DM];
    __shared__ float lg[NG * OUTC];
    __shared__ float mu[OUTC], inv[OUTC];
    const int t = threadIdx.x;

    for (int i = t; i < NG * DM; i += blockDim.x) {
        int g = i >> 7;
        ge[i] = sums[i] / fmaxf(cnt[g], 1.0f);
    }
    __syncthreads();

    for (int i = t; i < NG * OUTC; i += blockDim.x) {
        int g = i >> 5, o = i & (OUTC - 1);
        float acc = bfc[o];
#pragma unroll
        for (int k = 0; k < DM; ++k) acc += ge[g * DM + k] * Wfc[k * OUTC + o];
        lg[i] = acc;
    }
    __syncthreads();

    if (t < OUTC) {
        float s = 0.f;
        for (int g = 0; g < NG; ++g) s += lg[g * OUTC + t];
        float m = s * (1.f / NG);
        float v = 0.f;
        for (int g = 0; g < NG; ++g) { float d = lg[g * OUTC + t] - m; v += d * d; }
        v *= (1.f / NG);
        mu[t] = m;
        inv[t] = rsqrtf(v + EPS) * bn_g[t];
    }
    __syncthreads();

    for (int i = t; i < NG * OUTC; i += blockDim.x) {
        int o = i & (OUTC - 1);
        out[i] = (lg[i] - mu[o]) * inv[o] + bn_b[o];
    }
}

// ---------------------------------------------------------------------------
extern "C" void kernel_launch(void* const* d_in, const int* in_sizes, int n_in,
                              void* d_out, int out_size, void* d_ws, size_t ws_size,
                              hipStream_t stream)
{
    const float* x     = (const float*)d_in[0];
    const int*   ei    = (const int*)  d_in[1];
    const int*   batch = (const int*)  d_in[2];
    const float* W1    = (const float*)d_in[3];
    const float* as1   = (const float*)d_in[4];
    const float* ad1   = (const float*)d_in[5];
    const float* b1    = (const float*)d_in[6];
    const float* ln1g  = (const float*)d_in[7];
    const float* ln1b  = (const float*)d_in[8];
    const float* Wskip = (const float*)d_in[9];
    const float* bskip = (const float*)d_in[10];
    const float* W2    = (const float*)d_in[11];
    const float* as2   = (const float*)d_in[12];
    const float* ad2   = (const float*)d_in[13];
    const float* b2    = (const float*)d_in[14];
    const float* ln2g  = (const float*)d_in[15];
    const float* ln2b  = (const float*)d_in[16];
    const float* Wfc   = (const float*)d_in[17];
    const float* bfc   = (const float*)d_in[18];
    const float* bng   = (const float*)d_in[19];
    const float* bnb   = (const float*)d_in[20];

    const int N  = in_sizes[2];
    const int E  = in_sizes[1] / 2;

    size_t off = 0;
    auto alloc = [&](size_t bytes) -> char* {
        char* p = (char*)d_ws + off;
        off += (bytes + 255) & ~(size_t)255;
        return p;
    };
    unsigned short* Hbuf = (unsigned short*)alloc((size_t)N * DM * 2);  // bf16 h1/h2
    float* Buf1   = (float*)alloc((size_t)N * DM * 4);   // x1 (kept for residual)
    float* Buf2   = (float*)alloc((size_t)N * DM * 4);   // skip -> emb
    float* asrc   = (float*)alloc((size_t)N * NHEAD * 4);
    float* adst   = (float*)alloc((size_t)N * NHEAD * 4);
    int*   deg    = (int*)  alloc((size_t)N * 4);
    int*   rowptr = (int*)  alloc((size_t)(N + 1) * 4);
    int*   cursor = (int*)  alloc((size_t)N * 4);
    int*   col    = (int*)  alloc((size_t)E * 4);
    float* sums   = (float*)alloc((size_t)(NG * DM + NG) * 4);
    float* cnt    = sums + NG * DM;

    const int eb = (E + 255) / 256;
    const int gb = (N + TM - 1) / TM;
    const int ab = (N + 1) / 2;

    // ---- CSR build (shared by both layers) ----
    hipMemsetAsync(deg, 0, (size_t)N * 4, stream);
    deg_kernel<<<eb, 256, 0, stream>>>(ei, E, deg);
    scan_kernel<<<1, 1024, 0, stream>>>(deg, N, rowptr, cursor);
    scatter_kernel<<<eb, 256, 0, stream>>>(ei, E, cursor, col);

    // ---- layer 1 ----
    gemm_tile_kernel<<<gb, 256, 0, stream>>>(x, N, W1, nullptr, as1, ad1,
                                             nullptr, Hbuf, asrc, adst);
    gemm_tile_kernel<<<gb, 256, 0, stream>>>(x, N, Wskip, bskip, nullptr, nullptr,
                                             Buf2, nullptr, nullptr, nullptr);
    gat_agg_ln_kernel<<<ab, 128, 0, stream>>>(rowptr, col, Hbuf, asrc, adst,
                                              b1, nullptr, ln1g, ln1b, Buf2, Buf1, N);

    // ---- layer 2 ----
    gemm_tile_kernel<<<gb, 256, 0, stream>>>(Buf1, N, W2, nullptr, as2, ad2,
                                             nullptr, Hbuf, asrc, adst);
    gat_agg_ln_kernel<<<ab, 128, 0, stream>>>(rowptr, col, Hbuf, asrc, adst,
                                              b2, Buf1, ln2g, ln2b, nullptr, Buf2, N);

    // ---- pool + head ----
    hipMemsetAsync(sums, 0, (size_t)(NG * DM + NG) * 4, stream);
    pool_kernel<<<1024, DM, 0, stream>>>(Buf2, batch, N, sums, cnt);
    head_kernel<<<1, 1024, 0, stream>>>(sums, cnt, Wfc, bfc, bng, bnb, (float*)d_out);
}

// Round 9
// 358.443 us; speedup vs baseline: 9.3201x; 1.0937x over previous
//
#include <hip/hip_runtime.h>

#define DM    128
#define NHEAD 2
#define HIDC  64
#define OUTC  32
#define NG    64
#define EPS   1e-5f

typedef __attribute__((ext_vector_type(8))) short bf16x8;
typedef __attribute__((ext_vector_type(4))) float f32x4;

__device__ __forceinline__ unsigned short f2bf(float f) {
    union { float f; unsigned int u; } v; v.f = f;
    unsigned int r = v.u + 0x7fffu + ((v.u >> 16) & 1u);   // RNE
    return (unsigned short)(r >> 16);
}
__device__ __forceinline__ float bflo(unsigned int u) {
    union { unsigned int u; float f; } v; v.u = u << 16; return v.f;
}
__device__ __forceinline__ float bfhi(unsigned int u) {
    union { unsigned int u; float f; } v; v.u = u & 0xffff0000u; return v.f;
}

// ---------------------------------------------------------------------------
// MFMA GEMM: C = X @ W (+bias) (+att dots), X fp32 [N][128], W fp32 [128][128].
// 256 thr = 4 waves; each wave owns one 16-row tile (full 128 cols) per
// grid-stride step. B-fragments (W as bf16) live in registers, loaded once
// per block. A-fragments loaded directly from global (32B/lane contiguous).
// No LDS, no barriers. mfma_f32_16x16x32_bf16:
//   A: row=lane&15, k=(lane>>4)*8+j ; B: col=lane&15, k=(lane>>4)*8+j
//   C: col=lane&15, row=(lane>>4)*4+reg   (verified layout)
// ---------------------------------------------------------------------------
__global__ __launch_bounds__(256) void mfma_gemm_kernel(
    const float* __restrict__ X, int N,
    const float* __restrict__ W,
    const float* __restrict__ bias,      // nullable
    const float* __restrict__ att_src,   // nullable (with att_dst)
    const float* __restrict__ att_dst,
    float* __restrict__ C,               // fp32 out (nullable)
    unsigned short* __restrict__ Cbf,    // bf16 out (nullable)
    float* __restrict__ a_src,
    float* __restrict__ a_dst)
{
    const int lane = threadIdx.x & 63;
    const int wave = threadIdx.x >> 6;
    const int col  = lane & 15;
    const int kgrp = lane >> 4;          // 0..3

    // ---- B fragments: 8 N-tiles x 4 K-steps, once per block ----
    bf16x8 bfrag[8][4];
#pragma unroll
    for (int nt = 0; nt < 8; ++nt) {
#pragma unroll
        for (int ks = 0; ks < 4; ++ks) {
            const int c  = nt * 16 + col;
            const int k0 = ks * 32 + kgrp * 8;
            bf16x8 f;
#pragma unroll
            for (int j = 0; j < 8; ++j)
                f[j] = (short)f2bf(W[(k0 + j) * DM + c]);
            bfrag[nt][ks] = f;
        }
    }

    float bcol[8];
#pragma unroll
    for (int nt = 0; nt < 8; ++nt)
        bcol[nt] = bias ? bias[nt * 16 + col] : 0.f;

    float as_c[8], ad_c[8];
    if (att_src) {
#pragma unroll
        for (int nt = 0; nt < 8; ++nt) {
            as_c[nt] = att_src[nt * 16 + col];
            ad_c[nt] = att_dst[nt * 16 + col];
        }
    }

    const int ntiles = (N + 15) >> 4;
    for (int tile = blockIdx.x * 4 + wave; tile < ntiles; tile += gridDim.x * 4) {
        const int row0 = tile * 16;

        f32x4 acc[8];
#pragma unroll
        for (int nt = 0; nt < 8; ++nt) acc[nt] = (f32x4){0.f, 0.f, 0.f, 0.f};

#pragma unroll
        for (int ks = 0; ks < 4; ++ks) {
            const int r  = min(row0 + col, N - 1);   // clamp (N%16==0 normally)
            const int k0 = ks * 32 + kgrp * 8;
            const float4 x0 = *(const float4*)&X[(size_t)r * DM + k0];
            const float4 x1 = *(const float4*)&X[(size_t)r * DM + k0 + 4];
            bf16x8 af;
            af[0] = (short)f2bf(x0.x); af[1] = (short)f2bf(x0.y);
            af[2] = (short)f2bf(x0.z); af[3] = (short)f2bf(x0.w);
            af[4] = (short)f2bf(x1.x); af[5] = (short)f2bf(x1.y);
            af[6] = (short)f2bf(x1.z); af[7] = (short)f2bf(x1.w);
#pragma unroll
            for (int nt = 0; nt < 8; ++nt)
                acc[nt] = __builtin_amdgcn_mfma_f32_16x16x32_bf16(
                              af, bfrag[nt][ks], acc[nt], 0, 0, 0);
        }

        // epilogue: lane holds C[row0 + kgrp*4 + reg][nt*16 + col]
        float dots[4][2], dotd[4][2];
        if (att_src) {
#pragma unroll
            for (int reg = 0; reg < 4; ++reg) {
                dots[reg][0] = dots[reg][1] = 0.f;
                dotd[reg][0] = dotd[reg][1] = 0.f;
            }
        }
#pragma unroll
        for (int reg = 0; reg < 4; ++reg) {
            const int row = row0 + kgrp * 4 + reg;
            const bool ok = row < N;
#pragma unroll
            for (int nt = 0; nt < 8; ++nt) {
                const float o = acc[nt][reg] + bcol[nt];
                if (ok) {
                    if (Cbf) Cbf[(size_t)row * DM + nt * 16 + col] = f2bf(o);
                    else     C  [(size_t)row * DM + nt * 16 + col] = o;
                }
                if (att_src) {
                    dots[reg][nt >> 2] += o * as_c[nt];
                    dotd[reg][nt >> 2] += o * ad_c[nt];
                }
            }
        }
        if (att_src) {
#pragma unroll
            for (int reg = 0; reg < 4; ++reg) {
#pragma unroll
                for (int h = 0; h < 2; ++h) {
                    float vs = dots[reg][h], vd = dotd[reg][h];
#pragma unroll
                    for (int off = 8; off; off >>= 1) {
                        vs += __shfl_xor(vs, off);
                        vd += __shfl_xor(vd, off);
                    }
                    const int row = row0 + kgrp * 4 + reg;
                    if (col == 0 && row < N) {
                        a_src[row * NHEAD + h] = vs;
                        a_dst[row * NHEAD + h] = vd;
                    }
                }
            }
        }
    }
}

// ---------------------------------------------------------------------------
// CSR build: degree histogram -> exclusive scan -> range-filtered scatter.
// ---------------------------------------------------------------------------
__global__ void deg_kernel(const int* __restrict__ ei, int E, int* __restrict__ deg)
{
    int e = blockIdx.x * blockDim.x + threadIdx.x;
    if (e < E) atomicAdd(&deg[ei[E + e]], 1);
}

__global__ void scan_kernel(const int* __restrict__ deg, int N,
                            int* __restrict__ rowptr, int* __restrict__ cursor)
{
    __shared__ int wsum[16];
    __shared__ int carry_s;
    const int t = threadIdx.x;
    const int lane = t & 63, w = t >> 6;
    if (t == 0) carry_s = 0;
    __syncthreads();
    for (int base = 0; base < N; base += 1024) {
        const int i = base + t;
        const int v = (i < N) ? deg[i] : 0;
        int s = v;
#pragma unroll
        for (int off = 1; off < 64; off <<= 1) {
            int u = __shfl_up(s, off);
            if (lane >= off) s += u;
        }
        if (lane == 63) wsum[w] = s;
        __syncthreads();
        if (w == 0 && lane < 16) {
            int ws = wsum[lane];
            int ss = ws;
#pragma unroll
            for (int off = 1; off < 16; off <<= 1) {
                int u = __shfl_up(ss, off);
                if (lane >= off) ss += u;
            }
            wsum[lane] = ss - ws;
        }
        __syncthreads();
        const int excl = carry_s + wsum[w] + s - v;
        if (i < N) { rowptr[i] = excl; cursor[i] = excl; }
        __syncthreads();
        if (t == 1023) carry_s += wsum[15] + s;
        __syncthreads();
    }
    if (t == 0) rowptr[N] = carry_s;
}

// 256 blocks = 32 edge-slices x 8 dst-ranges (range = blockIdx&7 ~ XCD).
// Each block scans its slice, keeps edges with dst in its range -> col
// cachelines are written within one XCD's L2 and written back once.
__global__ void scatter_kernel(const int* __restrict__ ei, int E, int N,
                               int* __restrict__ cursor, int* __restrict__ col)
{
    const int range  = blockIdx.x & 7;
    const int slice  = blockIdx.x >> 3;
    const int nslice = gridDim.x >> 3;
    const int lo = range * (N >> 3);
    const int hi = (range == 7) ? N : lo + (N >> 3);
    const int per = (E + nslice - 1) / nslice;
    const int e0 = slice * per;
    const int e1 = min(E, e0 + per);
    for (int e = e0 + threadIdx.x; e < e1; e += blockDim.x) {
        const int d = ei[E + e];
        if (d >= lo && d < hi) {
            const int p = atomicAdd(&cursor[d], 1);
            col[p] = ei[e];
        }
    }
}

// ---------------------------------------------------------------------------
// Fused GAT aggregation + bias + (res) + LayerNorm + ELU + (skip).
// One wave per dst node, 2 channels/thread via u32 bf16x2 loads.
// ---------------------------------------------------------------------------
__global__ __launch_bounds__(128) void gat_agg_ln_kernel(
    const int* __restrict__ rowptr,
    const int* __restrict__ col,
    const unsigned short* __restrict__ H,   // bf16
    const float* __restrict__ a_src,
    const float* __restrict__ a_dst,
    const float* __restrict__ bias,
    const float* __restrict__ res,    // nullable, pre-LN
    const float* __restrict__ lng,
    const float* __restrict__ lnb,
    const float* __restrict__ skip,   // nullable, post-ELU
    float* __restrict__ out, int N)
{
    const int wid  = threadIdx.x >> 6;
    const int d    = blockIdx.x * 2 + wid;
    if (d >= N) return;
    const int lane = threadIdx.x & 63;
    const int half = lane >> 5;
    const int c2   = lane * 2;

    const float ad_h = a_dst[d * NHEAD + half];

    float e0 = a_src[d * NHEAD + half] + ad_h;
    e0 = e0 > 0.f ? e0 : 0.2f * e0;
    const float wself = __expf(e0);
    float den = wself;
    float2 acc;
    {
        const unsigned int hu = *(const unsigned int*)&H[d * DM + c2];
        acc.x = wself * bflo(hu);
        acc.y = wself * bfhi(hu);
    }

    const int p0 = rowptr[d], p1 = rowptr[d + 1];
    for (int base = p0; base < p1; base += 32) {
        const int m = min(32, p1 - base);
        const int el = lane & 31;

        float we = 0.f;
        int s = 0;
        if (el < m) {
            s = col[base + el];
            float a = a_src[s * NHEAD + half] + ad_h;
            a = a > 0.f ? a : 0.2f * a;
            we = __expf(a);
        }
        float ws = we;
#pragma unroll
        for (int off = 1; off < 32; off <<= 1) ws += __shfl_xor(ws, off);
        den += ws;

        const int hsel = lane & 32;
        int e = 0;
        for (; e + 4 <= m; e += 4) {
            const int s0 = __shfl(s, e),     s1 = __shfl(s, e + 1);
            const int s2 = __shfl(s, e + 2), s3 = __shfl(s, e + 3);
            const float w0 = __shfl(we, hsel | e),       w1 = __shfl(we, hsel | (e + 1));
            const float w2 = __shfl(we, hsel | (e + 2)), w3 = __shfl(we, hsel | (e + 3));
            const unsigned int u0 = *(const unsigned int*)&H[s0 * DM + c2];
            const unsigned int u1 = *(const unsigned int*)&H[s1 * DM + c2];
            const unsigned int u2 = *(const unsigned int*)&H[s2 * DM + c2];
            const unsigned int u3 = *(const unsigned int*)&H[s3 * DM + c2];
            acc.x += w0 * bflo(u0) + w1 * bflo(u1) + w2 * bflo(u2) + w3 * bflo(u3);
            acc.y += w0 * bfhi(u0) + w1 * bfhi(u1) + w2 * bfhi(u2) + w3 * bfhi(u3);
        }
        for (; e < m; ++e) {
            const int sE = __shfl(s, e);
            const float wE = __shfl(we, hsel | e);
            const unsigned int uE = *(const unsigned int*)&H[sE * DM + c2];
            acc.x += wE * bflo(uE);
            acc.y += wE * bfhi(uE);
        }
    }

    const int ibase = d * DM + c2;
    const float2 bv = *(const float2*)&bias[c2];
    float vx = acc.x / den + bv.x;
    float vy = acc.y / den + bv.y;
    if (res) {
        const float2 r = *(const float2*)&res[ibase];
        vx += r.x; vy += r.y;
    }

    float sm = vx + vy;
#pragma unroll
    for (int off = 1; off < 64; off <<= 1) sm += __shfl_xor(sm, off);
    const float mean = sm * (1.f / DM);

    const float dx = vx - mean, dy = vy - mean;
    float s2 = dx * dx + dy * dy;
#pragma unroll
    for (int off = 1; off < 64; off <<= 1) s2 += __shfl_xor(s2, off);
    const float rstd = rsqrtf(s2 * (1.f / DM) + EPS);

    const float2 gv = *(const float2*)&lng[c2];
    const float2 bb = *(const float2*)&lnb[c2];
    float yx = dx * rstd * gv.x + bb.x;
    float yy = dy * rstd * gv.y + bb.y;
    yx = yx > 0.f ? yx : expm1f(yx);
    yy = yy > 0.f ? yy : expm1f(yy);
    if (skip) {
        const float2 sk = *(const float2*)&skip[ibase];
        yx += sk.x; yy += sk.y;
    }
    *(float2*)&out[ibase] = make_float2(yx, yy);
}

// ---------------------------------------------------------------------------
// Global mean pool: sorted batch -> per-block register runs, few atomics.
// ---------------------------------------------------------------------------
__global__ void pool_kernel(const float* __restrict__ emb,
                            const int* __restrict__ batch, int N,
                            float* __restrict__ sums,
                            float* __restrict__ cnt)
{
    const int t = threadIdx.x;
    const int chunk = (N + gridDim.x - 1) / gridDim.x;
    const int n0 = blockIdx.x * chunk;
    const int n1 = min(N, n0 + chunk);
    if (n0 >= n1) return;

    int cur = batch[n0];
    float acc = 0.f;
    int count = 0;
    for (int n = n0; n < n1; ++n) {
        int b = batch[n];
        if (b != cur) {
            atomicAdd(&sums[cur * DM + t], acc);
            if (t == 0) atomicAdd(&cnt[cur], (float)count);
            acc = 0.f; count = 0; cur = b;
        }
        acc += emb[n * DM + t];
        ++count;
    }
    atomicAdd(&sums[cur * DM + t], acc);
    if (t == 0) atomicAdd(&cnt[cur], (float)count);
}

// ---------------------------------------------------------------------------
// Head: graph_emb = sums/cnt; logits = ge @ Wfc + bfc; BatchNorm over graphs.
// ---------------------------------------------------------------------------
__global__ void head_kernel(const float* __restrict__ sums,
                            const float* __restrict__ cnt,
                            const float* __restrict__ Wfc,
                            const float* __restrict__ bfc,
                            const float* __restrict__ bn_g,
                            const float* __restrict__ bn_b,
                            float* __restrict__ out)
{
    __shared__ float ge[NG * DM];
    __shared__ float lg[NG * OUTC];
    __shared__ float mu[OUTC], inv[OUTC];
    const int t = threadIdx.x;

    for (int i = t; i < NG * DM; i += blockDim.x) {
        int g = i >> 7;
        ge[i] = sums[i] / fmaxf(cnt[g], 1.0f);
    }
    __syncthreads();

    for (int i = t; i < NG * OUTC; i += blockDim.x) {
        int g = i >> 5, o = i & (OUTC - 1);
        float acc = bfc[o];
#pragma unroll
        for (int k = 0; k < DM; ++k) acc += ge[g * DM + k] * Wfc[k * OUTC + o];
        lg[i] = acc;
    }
    __syncthreads();

    if (t < OUTC) {
        float s = 0.f;
        for (int g = 0; g < NG; ++g) s += lg[g * OUTC + t];
        float m = s * (1.f / NG);
        float v = 0.f;
        for (int g = 0; g < NG; ++g) { float d = lg[g * OUTC + t] - m; v += d * d; }
        v *= (1.f / NG);
        mu[t] = m;
        inv[t] = rsqrtf(v + EPS) * bn_g[t];
    }
    __syncthreads();

    for (int i = t; i < NG * OUTC; i += blockDim.x) {
        int o = i & (OUTC - 1);
        out[i] = (lg[i] - mu[o]) * inv[o] + bn_b[o];
    }
}

// ---------------------------------------------------------------------------
extern "C" void kernel_launch(void* const* d_in, const int* in_sizes, int n_in,
                              void* d_out, int out_size, void* d_ws, size_t ws_size,
                              hipStream_t stream)
{
    const float* x     = (const float*)d_in[0];
    const int*   ei    = (const int*)  d_in[1];
    const int*   batch = (const int*)  d_in[2];
    const float* W1    = (const float*)d_in[3];
    const float* as1   = (const float*)d_in[4];
    const float* ad1   = (const float*)d_in[5];
    const float* b1    = (const float*)d_in[6];
    const float* ln1g  = (const float*)d_in[7];
    const float* ln1b  = (const float*)d_in[8];
    const float* Wskip = (const float*)d_in[9];
    const float* bskip = (const float*)d_in[10];
    const float* W2    = (const float*)d_in[11];
    const float* as2   = (const float*)d_in[12];
    const float* ad2   = (const float*)d_in[13];
    const float* b2    = (const float*)d_in[14];
    const float* ln2g  = (const float*)d_in[15];
    const float* ln2b  = (const float*)d_in[16];
    const float* Wfc   = (const float*)d_in[17];
    const float* bfc   = (const float*)d_in[18];
    const float* bng   = (const float*)d_in[19];
    const float* bnb   = (const float*)d_in[20];

    const int N  = in_sizes[2];
    const int E  = in_sizes[1] / 2;

    size_t off = 0;
    auto alloc = [&](size_t bytes) -> char* {
        char* p = (char*)d_ws + off;
        off += (bytes + 255) & ~(size_t)255;
        return p;
    };
    unsigned short* Hbuf = (unsigned short*)alloc((size_t)N * DM * 2);  // bf16 h1/h2
    float* Buf1   = (float*)alloc((size_t)N * DM * 4);   // x1 (kept for residual)
    float* Buf2   = (float*)alloc((size_t)N * DM * 4);   // skip -> emb
    float* asrc   = (float*)alloc((size_t)N * NHEAD * 4);
    float* adst   = (float*)alloc((size_t)N * NHEAD * 4);
    int*   deg    = (int*)  alloc((size_t)N * 4);
    int*   rowptr = (int*)  alloc((size_t)(N + 1) * 4);
    int*   cursor = (int*)  alloc((size_t)N * 4);
    int*   col    = (int*)  alloc((size_t)E * 4);
    float* sums   = (float*)alloc((size_t)(NG * DM + NG) * 4);
    float* cnt    = sums + NG * DM;

    const int eb = (E + 255) / 256;
    const int ab = (N + 1) / 2;

    // ---- CSR build (shared by both layers) ----
    hipMemsetAsync(deg, 0, (size_t)N * 4, stream);
    deg_kernel<<<eb, 256, 0, stream>>>(ei, E, deg);
    scan_kernel<<<1, 1024, 0, stream>>>(deg, N, rowptr, cursor);
    scatter_kernel<<<256, 256, 0, stream>>>(ei, E, N, cursor, col);

    // ---- layer 1 ----
    mfma_gemm_kernel<<<256, 256, 0, stream>>>(x, N, W1, nullptr, as1, ad1,
                                              nullptr, Hbuf, asrc, adst);
    mfma_gemm_kernel<<<256, 256, 0, stream>>>(x, N, Wskip, bskip, nullptr, nullptr,
                                              Buf2, nullptr, nullptr, nullptr);
    gat_agg_ln_kernel<<<ab, 128, 0, stream>>>(rowptr, col, Hbuf, asrc, adst,
                                              b1, nullptr, ln1g, ln1b, Buf2, Buf1, N);

    // ---- layer 2 ----
    mfma_gemm_kernel<<<256, 256, 0, stream>>>(Buf1, N, W2, nullptr, as2, ad2,
                                              nullptr, Hbuf, asrc, adst);
    gat_agg_ln_kernel<<<ab, 128, 0, stream>>>(rowptr, col, Hbuf, asrc, adst,
                                              b2, Buf1, ln2g, ln2b, nullptr, Buf2, N);

    // ---- pool + head ----
    hipMemsetAsync(sums, 0, (size_t)(NG * DM + NG) * 4, stream);
    pool_kernel<<<1024, DM, 0, stream>>>(Buf2, batch, N, sums, cnt);
    head_kernel<<<1, 1024, 0, stream>>>(sums, cnt, Wfc, bfc, bng, bnb, (float*)d_out);
}

// Round 10
// 279.355 us; speedup vs baseline: 11.9587x; 1.2831x over previous
//
#include <hip/hip_runtime.h>

#define DM    128
#define NHEAD 2
#define HIDC  64
#define OUTC  32
#define NG    64
#define EPS   1e-5f

typedef __attribute__((ext_vector_type(8))) short bf16x8;
typedef __attribute__((ext_vector_type(4))) float f32x4;

__device__ __forceinline__ unsigned short f2bf(float f) {
    union { float f; unsigned int u; } v; v.f = f;
    unsigned int r = v.u + 0x7fffu + ((v.u >> 16) & 1u);   // RNE
    return (unsigned short)(r >> 16);
}
__device__ __forceinline__ float bflo(unsigned int u) {
    union { unsigned int u; float f; } v; v.u = u << 16; return v.f;
}
__device__ __forceinline__ float bfhi(unsigned int u) {
    union { unsigned int u; float f; } v; v.u = u & 0xffff0000u; return v.f;
}

// ---------------------------------------------------------------------------
// MFMA GEMM: C = X @ W (+bias) (+att dots). B-fragments in registers,
// A loaded straight from global. No LDS, no barriers. (unchanged from R8)
// ---------------------------------------------------------------------------
__global__ __launch_bounds__(256) void mfma_gemm_kernel(
    const float* __restrict__ X, int N,
    const float* __restrict__ W,
    const float* __restrict__ bias,      // nullable
    const float* __restrict__ att_src,   // nullable (with att_dst)
    const float* __restrict__ att_dst,
    float* __restrict__ C,               // fp32 out (nullable)
    unsigned short* __restrict__ Cbf,    // bf16 out (nullable)
    float* __restrict__ a_src,
    float* __restrict__ a_dst)
{
    const int lane = threadIdx.x & 63;
    const int wave = threadIdx.x >> 6;
    const int col  = lane & 15;
    const int kgrp = lane >> 4;          // 0..3

    bf16x8 bfrag[8][4];
#pragma unroll
    for (int nt = 0; nt < 8; ++nt) {
#pragma unroll
        for (int ks = 0; ks < 4; ++ks) {
            const int c  = nt * 16 + col;
            const int k0 = ks * 32 + kgrp * 8;
            bf16x8 f;
#pragma unroll
            for (int j = 0; j < 8; ++j)
                f[j] = (short)f2bf(W[(k0 + j) * DM + c]);
            bfrag[nt][ks] = f;
        }
    }

    float bcol[8];
#pragma unroll
    for (int nt = 0; nt < 8; ++nt)
        bcol[nt] = bias ? bias[nt * 16 + col] : 0.f;

    float as_c[8], ad_c[8];
    if (att_src) {
#pragma unroll
        for (int nt = 0; nt < 8; ++nt) {
            as_c[nt] = att_src[nt * 16 + col];
            ad_c[nt] = att_dst[nt * 16 + col];
        }
    }

    const int ntiles = (N + 15) >> 4;
    for (int tile = blockIdx.x * 4 + wave; tile < ntiles; tile += gridDim.x * 4) {
        const int row0 = tile * 16;

        f32x4 acc[8];
#pragma unroll
        for (int nt = 0; nt < 8; ++nt) acc[nt] = (f32x4){0.f, 0.f, 0.f, 0.f};

#pragma unroll
        for (int ks = 0; ks < 4; ++ks) {
            const int r  = min(row0 + col, N - 1);
            const int k0 = ks * 32 + kgrp * 8;
            const float4 x0 = *(const float4*)&X[(size_t)r * DM + k0];
            const float4 x1 = *(const float4*)&X[(size_t)r * DM + k0 + 4];
            bf16x8 af;
            af[0] = (short)f2bf(x0.x); af[1] = (short)f2bf(x0.y);
            af[2] = (short)f2bf(x0.z); af[3] = (short)f2bf(x0.w);
            af[4] = (short)f2bf(x1.x); af[5] = (short)f2bf(x1.y);
            af[6] = (short)f2bf(x1.z); af[7] = (short)f2bf(x1.w);
#pragma unroll
            for (int nt = 0; nt < 8; ++nt)
                acc[nt] = __builtin_amdgcn_mfma_f32_16x16x32_bf16(
                              af, bfrag[nt][ks], acc[nt], 0, 0, 0);
        }

        float dots[4][2], dotd[4][2];
        if (att_src) {
#pragma unroll
            for (int reg = 0; reg < 4; ++reg) {
                dots[reg][0] = dots[reg][1] = 0.f;
                dotd[reg][0] = dotd[reg][1] = 0.f;
            }
        }
#pragma unroll
        for (int reg = 0; reg < 4; ++reg) {
            const int row = row0 + kgrp * 4 + reg;
            const bool ok = row < N;
#pragma unroll
            for (int nt = 0; nt < 8; ++nt) {
                const float o = acc[nt][reg] + bcol[nt];
                if (ok) {
                    if (Cbf) Cbf[(size_t)row * DM + nt * 16 + col] = f2bf(o);
                    else     C  [(size_t)row * DM + nt * 16 + col] = o;
                }
                if (att_src) {
                    dots[reg][nt >> 2] += o * as_c[nt];
                    dotd[reg][nt >> 2] += o * ad_c[nt];
                }
            }
        }
        if (att_src) {
#pragma unroll
            for (int reg = 0; reg < 4; ++reg) {
#pragma unroll
                for (int h = 0; h < 2; ++h) {
                    float vs = dots[reg][h], vd = dotd[reg][h];
#pragma unroll
                    for (int off = 8; off; off >>= 1) {
                        vs += __shfl_xor(vs, off);
                        vd += __shfl_xor(vd, off);
                    }
                    const int row = row0 + kgrp * 4 + reg;
                    if (col == 0 && row < N) {
                        a_src[row * NHEAD + h] = vs;
                        a_dst[row * NHEAD + h] = vd;
                    }
                }
            }
        }
    }
}

// ---------------------------------------------------------------------------
// CSR build: degree histogram -> 3-kernel two-level scan -> flat scatter.
// ---------------------------------------------------------------------------
__global__ void deg_kernel(const int* __restrict__ ei, int E, int* __restrict__ deg)
{
    int e = blockIdx.x * blockDim.x + threadIdx.x;
    if (e < E) atomicAdd(&deg[ei[E + e]], 1);
}

// k1: per-1024-chunk sums. 256 threads, 4 elems/thread.
__global__ __launch_bounds__(256) void scan_sums_kernel(
    const int* __restrict__ deg, int N, int* __restrict__ bsum)
{
    __shared__ int wtot[4];
    const int t = threadIdx.x, lane = t & 63, w = t >> 6;
    const int i0 = blockIdx.x * 1024 + t * 4;
    int s = 0;
#pragma unroll
    for (int k = 0; k < 4; ++k) { int i = i0 + k; if (i < N) s += deg[i]; }
#pragma unroll
    for (int off = 32; off; off >>= 1) s += __shfl_down(s, off);
    if (lane == 0) wtot[w] = s;
    __syncthreads();
    if (t == 0) bsum[blockIdx.x] = wtot[0] + wtot[1] + wtot[2] + wtot[3];
}

// k2: single wave scans the (<=1024) block sums -> exclusive boff, total -> rowptr[N].
__global__ void scan_partials_kernel(int* __restrict__ bsum, int nblk,
                                     int* __restrict__ boff, int* __restrict__ rowptrN)
{
    const int lane = threadIdx.x;   // 64 threads
    int carry = 0;
    for (int base = 0; base < nblk; base += 64) {
        const int i = base + lane;
        int v = (i < nblk) ? bsum[i] : 0;
        int s = v;
#pragma unroll
        for (int off = 1; off < 64; off <<= 1) {
            int u = __shfl_up(s, off);
            if (lane >= off) s += u;
        }
        if (i < nblk) boff[i] = carry + s - v;
        carry += __shfl(s, 63);
    }
    if (lane == 0) *rowptrN = carry;
}

// k3: per-chunk exclusive fill of rowptr + cursor.
__global__ __launch_bounds__(256) void scan_fill_kernel(
    const int* __restrict__ deg, int N, const int* __restrict__ boff,
    int* __restrict__ rowptr, int* __restrict__ cursor)
{
    __shared__ int woff[4];
    const int t = threadIdx.x, lane = t & 63, w = t >> 6;
    const int i0 = blockIdx.x * 1024 + t * 4;
    int v[4]; int ts = 0;
#pragma unroll
    for (int k = 0; k < 4; ++k) {
        int i = i0 + k;
        v[k] = (i < N) ? deg[i] : 0;
        ts += v[k];
    }
    int s = ts;
#pragma unroll
    for (int off = 1; off < 64; off <<= 1) {
        int u = __shfl_up(s, off);
        if (lane >= off) s += u;
    }
    if (lane == 63) woff[w] = s;        // wave total (inclusive of all lanes)
    __syncthreads();
    int wpre = 0;
#pragma unroll
    for (int k = 0; k < 4; ++k) if (k < w) wpre += woff[k];
    int off0 = boff[blockIdx.x] + wpre + (s - ts);
#pragma unroll
    for (int k = 0; k < 4; ++k) {
        int i = i0 + k;
        if (i < N) { rowptr[i] = off0; cursor[i] = off0; }
        off0 += v[k];
    }
}

// flat edge-parallel scatter; col is ushort (node ids < 65536).
__global__ void scatter_kernel(const int* __restrict__ ei, int E,
                               int* __restrict__ cursor,
                               unsigned short* __restrict__ col)
{
    int e = blockIdx.x * blockDim.x + threadIdx.x;
    if (e < E) {
        int d = ei[E + e];
        int p = atomicAdd(&cursor[d], 1);
        col[p] = (unsigned short)ei[e];
    }
}

// ---------------------------------------------------------------------------
// Fused GAT aggregation + bias + (res) + LayerNorm + ELU + (skip).
// One wave per dst node, 2 channels/thread via u32 bf16x2 loads.
// ---------------------------------------------------------------------------
__global__ __launch_bounds__(128) void gat_agg_ln_kernel(
    const int* __restrict__ rowptr,
    const unsigned short* __restrict__ col,
    const unsigned short* __restrict__ H,   // bf16
    const float* __restrict__ a_src,
    const float* __restrict__ a_dst,
    const float* __restrict__ bias,
    const float* __restrict__ res,    // nullable, pre-LN
    const float* __restrict__ lng,
    const float* __restrict__ lnb,
    const float* __restrict__ skip,   // nullable, post-ELU
    float* __restrict__ out, int N)
{
    const int wid  = threadIdx.x >> 6;
    const int d    = blockIdx.x * 2 + wid;
    if (d >= N) return;
    const int lane = threadIdx.x & 63;
    const int half = lane >> 5;
    const int c2   = lane * 2;

    const float ad_h = a_dst[d * NHEAD + half];

    float e0 = a_src[d * NHEAD + half] + ad_h;
    e0 = e0 > 0.f ? e0 : 0.2f * e0;
    const float wself = __expf(e0);
    float den = wself;
    float2 acc;
    {
        const unsigned int hu = *(const unsigned int*)&H[d * DM + c2];
        acc.x = wself * bflo(hu);
        acc.y = wself * bfhi(hu);
    }

    const int p0 = rowptr[d], p1 = rowptr[d + 1];
    for (int base = p0; base < p1; base += 32) {
        const int m = min(32, p1 - base);
        const int el = lane & 31;

        float we = 0.f;
        int s = 0;
        if (el < m) {
            s = (int)col[base + el];
            float a = a_src[s * NHEAD + half] + ad_h;
            a = a > 0.f ? a : 0.2f * a;
            we = __expf(a);
        }
        float ws = we;
#pragma unroll
        for (int off = 1; off < 32; off <<= 1) ws += __shfl_xor(ws, off);
        den += ws;

        const int hsel = lane & 32;
        int e = 0;
        for (; e + 4 <= m; e += 4) {
            const int s0 = __shfl(s, e),     s1 = __shfl(s, e + 1);
            const int s2 = __shfl(s, e + 2), s3 = __shfl(s, e + 3);
            const float w0 = __shfl(we, hsel | e),       w1 = __shfl(we, hsel | (e + 1));
            const float w2 = __shfl(we, hsel | (e + 2)), w3 = __shfl(we, hsel | (e + 3));
            const unsigned int u0 = *(const unsigned int*)&H[s0 * DM + c2];
            const unsigned int u1 = *(const unsigned int*)&H[s1 * DM + c2];
            const unsigned int u2 = *(const unsigned int*)&H[s2 * DM + c2];
            const unsigned int u3 = *(const unsigned int*)&H[s3 * DM + c2];
            acc.x += w0 * bflo(u0) + w1 * bflo(u1) + w2 * bflo(u2) + w3 * bflo(u3);
            acc.y += w0 * bfhi(u0) + w1 * bfhi(u1) + w2 * bfhi(u2) + w3 * bfhi(u3);
        }
        for (; e < m; ++e) {
            const int sE = __shfl(s, e);
            const float wE = __shfl(we, hsel | e);
            const unsigned int uE = *(const unsigned int*)&H[sE * DM + c2];
            acc.x += wE * bflo(uE);
            acc.y += wE * bfhi(uE);
        }
    }

    const int ibase = d * DM + c2;
    const float2 bv = *(const float2*)&bias[c2];
    float vx = acc.x / den + bv.x;
    float vy = acc.y / den + bv.y;
    if (res) {
        const float2 r = *(const float2*)&res[ibase];
        vx += r.x; vy += r.y;
    }

    float sm = vx + vy;
#pragma unroll
    for (int off = 1; off < 64; off <<= 1) sm += __shfl_xor(sm, off);
    const float mean = sm * (1.f / DM);

    const float dx = vx - mean, dy = vy - mean;
    float s2 = dx * dx + dy * dy;
#pragma unroll
    for (int off = 1; off < 64; off <<= 1) s2 += __shfl_xor(s2, off);
    const float rstd = rsqrtf(s2 * (1.f / DM) + EPS);

    const float2 gv = *(const float2*)&lng[c2];
    const float2 bb = *(const float2*)&lnb[c2];
    float yx = dx * rstd * gv.x + bb.x;
    float yy = dy * rstd * gv.y + bb.y;
    yx = yx > 0.f ? yx : expm1f(yx);
    yy = yy > 0.f ? yy : expm1f(yy);
    if (skip) {
        const float2 sk = *(const float2*)&skip[ibase];
        yx += sk.x; yy += sk.y;
    }
    *(float2*)&out[ibase] = make_float2(yx, yy);
}

// ---------------------------------------------------------------------------
// Global mean pool: sorted batch -> per-block register runs, few atomics.
// ---------------------------------------------------------------------------
__global__ void pool_kernel(const float* __restrict__ emb,
                            const int* __restrict__ batch, int N,
                            float* __restrict__ sums,
                            float* __restrict__ cnt)
{
    const int t = threadIdx.x;
    const int chunk = (N + gridDim.x - 1) / gridDim.x;
    const int n0 = blockIdx.x * chunk;
    const int n1 = min(N, n0 + chunk);
    if (n0 >= n1) return;

    int cur = batch[n0];
    float acc = 0.f;
    int count = 0;
    for (int n = n0; n < n1; ++n) {
        int b = batch[n];
        if (b != cur) {
            atomicAdd(&sums[cur * DM + t], acc);
            if (t == 0) atomicAdd(&cnt[cur], (float)count);
            acc = 0.f; count = 0; cur = b;
        }
        acc += emb[n * DM + t];
        ++count;
    }
    atomicAdd(&sums[cur * DM + t], acc);
    if (t == 0) atomicAdd(&cnt[cur], (float)count);
}

// ---------------------------------------------------------------------------
// Head: graph_emb = sums/cnt; logits = ge @ Wfc + bfc; BatchNorm over graphs.
// ---------------------------------------------------------------------------
__global__ void head_kernel(const float* __restrict__ sums,
                            const float* __restrict__ cnt,
                            const float* __restrict__ Wfc,
                            const float* __restrict__ bfc,
                            const float* __restrict__ bn_g,
                            const float* __restrict__ bn_b,
                            float* __restrict__ out)
{
    __shared__ float ge[NG * DM];
    __shared__ float lg[NG * OUTC];
    __shared__ float mu[OUTC], inv[OUTC];
    const int t = threadIdx.x;

    for (int i = t; i < NG * DM; i += blockDim.x) {
        int g = i >> 7;
        ge[i] = sums[i] / fmaxf(cnt[g], 1.0f);
    }
    __syncthreads();

    for (int i = t; i < NG * OUTC; i += blockDim.x) {
        int g = i >> 5, o = i & (OUTC - 1);
        float acc = bfc[o];
#pragma unroll
        for (int k = 0; k < DM; ++k) acc += ge[g * DM + k] * Wfc[k * OUTC + o];
        lg[i] = acc;
    }
    __syncthreads();

    if (t < OUTC) {
        float s = 0.f;
        for (int g = 0; g < NG; ++g) s += lg[g * OUTC + t];
        float m = s * (1.f / NG);
        float v = 0.f;
        for (int g = 0; g < NG; ++g) { float d = lg[g * OUTC + t] - m; v += d * d; }
        v *= (1.f / NG);
        mu[t] = m;
        inv[t] = rsqrtf(v + EPS) * bn_g[t];
    }
    __syncthreads();

    for (int i = t; i < NG * OUTC; i += blockDim.x) {
        int o = i & (OUTC - 1);
        out[i] = (lg[i] - mu[o]) * inv[o] + bn_b[o];
    }
}

// ---------------------------------------------------------------------------
extern "C" void kernel_launch(void* const* d_in, const int* in_sizes, int n_in,
                              void* d_out, int out_size, void* d_ws, size_t ws_size,
                              hipStream_t stream)
{
    const float* x     = (const float*)d_in[0];
    const int*   ei    = (const int*)  d_in[1];
    const int*   batch = (const int*)  d_in[2];
    const float* W1    = (const float*)d_in[3];
    const float* as1   = (const float*)d_in[4];
    const float* ad1   = (const float*)d_in[5];
    const float* b1    = (const float*)d_in[6];
    const float* ln1g  = (const float*)d_in[7];
    const float* ln1b  = (const float*)d_in[8];
    const float* Wskip = (const float*)d_in[9];
    const float* bskip = (const float*)d_in[10];
    const float* W2    = (const float*)d_in[11];
    const float* as2   = (const float*)d_in[12];
    const float* ad2   = (const float*)d_in[13];
    const float* b2    = (const float*)d_in[14];
    const float* ln2g  = (const float*)d_in[15];
    const float* ln2b  = (const float*)d_in[16];
    const float* Wfc   = (const float*)d_in[17];
    const float* bfc   = (const float*)d_in[18];
    const float* bng   = (const float*)d_in[19];
    const float* bnb   = (const float*)d_in[20];

    const int N  = in_sizes[2];
    const int E  = in_sizes[1] / 2;

    size_t off = 0;
    auto alloc = [&](size_t bytes) -> char* {
        char* p = (char*)d_ws + off;
        off += (bytes + 255) & ~(size_t)255;
        return p;
    };
    unsigned short* Hbuf = (unsigned short*)alloc((size_t)N * DM * 2);  // bf16 h1/h2
    float* Buf1   = (float*)alloc((size_t)N * DM * 4);   // x1 (kept for residual)
    float* Buf2   = (float*)alloc((size_t)N * DM * 4);   // skip -> emb
    float* asrc   = (float*)alloc((size_t)N * NHEAD * 4);
    float* adst   = (float*)alloc((size_t)N * NHEAD * 4);
    int*   deg    = (int*)  alloc((size_t)N * 4);
    int*   rowptr = (int*)  alloc((size_t)(N + 1) * 4);
    int*   cursor = (int*)  alloc((size_t)N * 4);
    int*   bsum   = (int*)  alloc((size_t)256 * 4);
    int*   boff   = (int*)  alloc((size_t)256 * 4);
    unsigned short* col = (unsigned short*)alloc((size_t)E * 2);
    float* sums   = (float*)alloc((size_t)(NG * DM + NG) * 4);
    float* cnt    = sums + NG * DM;

    const int eb   = (E + 255) / 256;
    const int ab   = (N + 1) / 2;
    const int nblk = (N + 1023) / 1024;

    // ---- CSR build (shared by both layers) ----
    hipMemsetAsync(deg, 0, (size_t)N * 4, stream);
    deg_kernel<<<eb, 256, 0, stream>>>(ei, E, deg);
    scan_sums_kernel<<<nblk, 256, 0, stream>>>(deg, N, bsum);
    scan_partials_kernel<<<1, 64, 0, stream>>>(bsum, nblk, boff, &rowptr[N]);
    scan_fill_kernel<<<nblk, 256, 0, stream>>>(deg, N, boff, rowptr, cursor);
    scatter_kernel<<<eb, 256, 0, stream>>>(ei, E, cursor, col);

    // ---- layer 1 ----
    mfma_gemm_kernel<<<256, 256, 0, stream>>>(x, N, W1, nullptr, as1, ad1,
                                              nullptr, Hbuf, asrc, adst);
    mfma_gemm_kernel<<<256, 256, 0, stream>>>(x, N, Wskip, bskip, nullptr, nullptr,
                                              Buf2, nullptr, nullptr, nullptr);
    gat_agg_ln_kernel<<<ab, 128, 0, stream>>>(rowptr, col, Hbuf, asrc, adst,
                                              b1, nullptr, ln1g, ln1b, Buf2, Buf1, N);

    // ---- layer 2 ----
    mfma_gemm_kernel<<<256, 256, 0, stream>>>(Buf1, N, W2, nullptr, as2, ad2,
                                              nullptr, Hbuf, asrc, adst);
    gat_agg_ln_kernel<<<ab, 128, 0, stream>>>(rowptr, col, Hbuf, asrc, adst,
                                              b2, Buf1, ln2g, ln2b, nullptr, Buf2, N);

    // ---- pool + head ----
    hipMemsetAsync(sums, 0, (size_t)(NG * DM + NG) * 4, stream);
    pool_kernel<<<1024, DM, 0, stream>>>(Buf2, batch, N, sums, cnt);
    head_kernel<<<1, 1024, 0, stream>>>(sums, cnt, Wfc, bfc, bng, bnb, (float*)d_out);
}